// Round 6
// baseline (1697.573 us; speedup 1.0000x reference)
//
#include <hip/hip_runtime.h>

typedef unsigned short u16;
typedef unsigned int   u32;

// ---------- bf16 helpers ----------
__device__ __forceinline__ float b2f(u16 h){ return __uint_as_float(((u32)h)<<16); }
__device__ __forceinline__ u16 f2b(float f){
  u32 u = __float_as_uint(f);
  u32 r = (u + 0x7fffu + ((u>>16)&1u)) >> 16;   // RNE
  return (u16)r;
}
__device__ __forceinline__ float leaky(float x, float s){ return x >= 0.f ? x : s*x; }

typedef __bf16 bf16x8 __attribute__((ext_vector_type(8)));
typedef float  f32x4  __attribute__((ext_vector_type(4)));

// load 8 contiguous source elems as 8 bf16 (u16)
__device__ __forceinline__ void load8(const u16* p, u16* h){ *(uint4*)h = *(const uint4*)p; }
__device__ __forceinline__ void load8(const float* p, u16* h){
  float4 a = *(const float4*)p; float4 b = *(const float4*)(p+4);
  h[0]=f2b(a.x); h[1]=f2b(a.y); h[2]=f2b(a.z); h[3]=f2b(a.w);
  h[4]=f2b(b.x); h[5]=f2b(b.y); h[6]=f2b(b.z); h[7]=f2b(b.w);
}

// ---------- int64-vs-int32 detection (odd 32b words of src row all-zero => int64) ----------
__global__ void k_detect(const u32* __restrict__ w, int E, u32* __restrict__ flag){
  u32 acc = 0;
  for (int i = blockIdx.x*256 + threadIdx.x; i < E; i += 256*gridDim.x)
    acc |= w[2*i + 1];
  __shared__ u32 s[256];
  s[threadIdx.x] = acc; __syncthreads();
  for (int o=128;o>0;o>>=1){ if (threadIdx.x<o) s[threadIdx.x] |= s[threadIdx.x+o]; __syncthreads(); }
  if (threadIdx.x==0 && s[0]) atomicOr(flag, 1u);   // nonzero -> int32
}

__device__ __forceinline__ void edge_sd(const int* __restrict__ ei, int E, int e, u32 is32,
                                        int& s, int& d){
  if (is32){ s = ei[e];   d = ei[E + e]; }
  else     { s = ei[2*e]; d = ei[2*E + 2*e]; }
}

// ---------- CSR build ----------
__global__ void k_hist(const int* __restrict__ ei, int E, int nN,
                       const u32* __restrict__ flag, int* __restrict__ cnt){
  int e = blockIdx.x*256 + threadIdx.x;
  if (e < E){
    int s,d; edge_sd(ei, E, e, *flag, s, d);
    if ((u32)s < (u32)nN && (u32)d < (u32)nN) atomicAdd(&cnt[d], 1);
  }
}

__global__ void k_scan_a(const int* __restrict__ cnt, int n, int* __restrict__ bsum){
  __shared__ int s[256];
  int base = blockIdx.x*1024, t = threadIdx.x, sum = 0;
  for (int j=0;j<4;j++){ int i = base + t*4 + j; if (i<n) sum += cnt[i]; }
  s[t] = sum; __syncthreads();
  for (int off=128; off>0; off>>=1){ if (t<off) s[t]+=s[t+off]; __syncthreads(); }
  if (t==0) bsum[blockIdx.x] = s[0];
}

__global__ void k_scan_b(int* bsum, int nb){
  if (threadIdx.x==0 && blockIdx.x==0){
    int acc = 0;
    for (int i=0;i<nb;i++){ int v = bsum[i]; bsum[i] = acc; acc += v; }
  }
}

__global__ void k_scan_c(const int* __restrict__ cnt, const int* __restrict__ bsum,
                         int n, int* __restrict__ offs){
  __shared__ int s[256];
  int base = blockIdx.x*1024, t = threadIdx.x;
  int v[4]; int sum=0;
  for (int j=0;j<4;j++){ int i=base+t*4+j; v[j] = (i<n)?cnt[i]:0; sum += v[j]; }
  s[t]=sum; __syncthreads();
  for (int off=1; off<256; off<<=1){
    int add = (t>=off)? s[t-off] : 0;
    __syncthreads();
    s[t] += add;
    __syncthreads();
  }
  int excl = (t ? s[t-1] : 0) + bsum[blockIdx.x];
  for (int j=0;j<4;j++){
    int i = base+t*4+j;
    if (i<n){ offs[i] = excl; excl += v[j]; if (i==n-1) offs[n] = excl; }
  }
}

__global__ void k_dinv2(const int* __restrict__ offs, int n, float* __restrict__ dinv){
  int i = blockIdx.x*256+threadIdx.x;
  if (i<n) dinv[i] = rsqrtf((float)(offs[i+1]-offs[i]) + 1.0f);
}

__global__ void k_scatter(const int* __restrict__ ei, int E, int nN,
                          const u32* __restrict__ flag, const int* __restrict__ offs,
                          int* __restrict__ cursor, int* __restrict__ csr){
  int e = blockIdx.x*256+threadIdx.x;
  if (e<E){
    int s,d; edge_sd(ei, E, e, *flag, s, d);
    if ((u32)s < (u32)nN && (u32)d < (u32)nN){
      int pos = offs[d] + atomicAdd(&cursor[d], 1);
      csr[pos] = s;
    }
  }
}

// ---------- transpose+convert: f32 (K x M) -> bf16 (M x K) ----------
__global__ void k_transpose(const float* __restrict__ in, u16* __restrict__ out, int K, int M){
  int i = blockIdx.x*256 + threadIdx.x;
  if (i < K*M){ int k = i / M, m = i % M; out[m*K + k] = f2b(in[i]); }
}

// ---------- MFMA GEMM: out[r][m] = sum_k A[r][k]*B[k][m] (+bias[m]); K=256, M=64 ----------
// A supplied as 4 column-pieces (64 cols each, f32 or bf16) with row stride rsA elements.
template<typename AT>
__global__ __launch_bounds__(256) void k_gemm64(
  const AT* __restrict__ A0, const AT* __restrict__ A1,
  const AT* __restrict__ A2, const AT* __restrict__ A3,
  int rsA, const u16* __restrict__ Bt, const float* __restrict__ bias,
  u16* __restrict__ out, int nRows)
{
  alignas(16) __shared__ u16 Al[64*264];
  alignas(16) __shared__ u16 Bl[32*264];
  const int t = threadIdx.x;
  const int r0 = blockIdx.x*64;
  for (int it=0; it<8; ++it){
    int c = t + it*256;
    int row = c>>5, seg = c&31;
    int gr = r0+row;
    u16 hv[8] = {0,0,0,0,0,0,0,0};
    if (gr < nRows){
      const AT* p = (seg<8)?A0 : (seg<16)?A1 : (seg<24)?A2 : A3;
      load8(p + (size_t)gr*rsA + (seg&7)*8, hv);
    }
    *(uint4*)&Al[row*264 + seg*8] = *(uint4*)hv;
  }
  const int lane=t&63, wid=t>>6, quad=lane>>4, l15=lane&15;
  const int abase=(wid*16+l15)*264 + quad*8;
  for (int cc=0; cc<2; ++cc){
    __syncthreads();
    for (int it=0; it<4; ++it){
      int c = t + it*256;
      int row=c>>5, seg=c&31;
      uint4 v = *(const uint4*)(Bt + (size_t)(cc*32+row)*256 + seg*8);
      *(uint4*)&Bl[row*264 + seg*8] = v;
    }
    __syncthreads();
    f32x4 a0={0.f,0.f,0.f,0.f}, a1={0.f,0.f,0.f,0.f};
    #pragma unroll
    for (int ks=0;ks<8;++ks){
      bf16x8 av = *(const bf16x8*)&Al[abase + ks*32];
      bf16x8 b0 = *(const bf16x8*)&Bl[(     l15)*264 + quad*8 + ks*32];
      bf16x8 b1 = *(const bf16x8*)&Bl[(16 + l15)*264 + quad*8 + ks*32];
      a0 = __builtin_amdgcn_mfma_f32_16x16x32_bf16(av,b0,a0,0,0,0);
      a1 = __builtin_amdgcn_mfma_f32_16x16x32_bf16(av,b1,a1,0,0,0);
    }
    #pragma unroll
    for (int half=0; half<2; ++half){
      f32x4 acc = half?a1:a0;
      int col = cc*32 + half*16 + l15;
      float bv = bias ? bias[col] : 0.f;
      #pragma unroll
      for (int reg=0;reg<4;++reg){
        int r = r0 + wid*16 + quad*4 + reg;   // C/D: col=lane&15, row=quad*4+reg
        if (r<nRows) out[(size_t)r*64+col] = f2b(acc[reg]+bv);
      }
    }
  }
}

// ---------- GCN gather, 64 channels, bf16 in/out (wave per node, unroll-4) ----------
__global__ void k_gather64(const u16* __restrict__ h, const int* __restrict__ offs,
                           const int* __restrict__ csr, const float* __restrict__ dinv,
                           const float* __restrict__ bias, int n, u16* __restrict__ out){
  int nd = blockIdx.x*4 + (threadIdx.x>>6);
  if (nd>=n) return;
  int lane = threadIdx.x&63;
  float dn = dinv[nd];
  float acc = dn*b2f(h[(size_t)nd*64+lane]);   // self: dn*dn*h ; factor dn applied at end
  int e = offs[nd], end = offs[nd+1];
  for (; e+4<=end; e+=4){
    int s0=csr[e], s1=csr[e+1], s2=csr[e+2], s3=csr[e+3];
    float w0=dinv[s0], w1=dinv[s1], w2=dinv[s2], w3=dinv[s3];
    float p0=b2f(h[(size_t)s0*64+lane]);
    float p1=b2f(h[(size_t)s1*64+lane]);
    float p2=b2f(h[(size_t)s2*64+lane]);
    float p3=b2f(h[(size_t)s3*64+lane]);
    acc += w0*p0 + w1*p1 + w2*p2 + w3*p3;
  }
  for (; e<end; ++e){
    int s=csr[e];
    acc += dinv[s]*b2f(h[(size_t)s*64+lane]);
  }
  out[(size_t)nd*64+lane] = f2b(dn*acc + bias[lane]);
}

// ---------- BN stats (grid-scalable: rows-per-block derived from gridDim) ----------
__global__ void k_stats_b16(const u16* __restrict__ x, int n, int C,
                            float* __restrict__ stats){
  int t = threadIdx.x;
  int c = t % C, sub = t / C, nsub = 256 / C;
  int rpb = (n + gridDim.x - 1) / gridDim.x;
  int base = blockIdx.x * rpb;
  int lim  = min(base + rpb, n);
  float s=0.f, s2=0.f;
  for (int row = base + sub; row < lim; row += nsub){
    float v = b2f(x[(size_t)row*C + c]); s += v; s2 += v*v;
  }
  atomicAdd(&stats[c], s);
  atomicAdd(&stats[C + c], s2);
}

__global__ void k_stats_f32(const float* __restrict__ x, int n, int C,
                            float* __restrict__ stats){
  int t = threadIdx.x;
  int c = t % C, sub = t / C, nsub = 256 / C;
  int rpb = (n + gridDim.x - 1) / gridDim.x;
  int base = blockIdx.x * rpb;
  int lim  = min(base + rpb, n);
  float s=0.f, s2=0.f;
  for (int row = base + sub; row < lim; row += nsub){
    float v = x[(size_t)row*C + c]; s += v; s2 += v*v;
  }
  atomicAdd(&stats[c], s);
  atomicAdd(&stats[C + c], s2);
}

__global__ void k_bnfin(const float* __restrict__ stats, const float* __restrict__ g,
                        const float* __restrict__ be, int C, float n, float* __restrict__ bnp){
  int c = threadIdx.x + blockIdx.x*256;
  if (c < C){
    float mu = stats[c]/n;
    float var = fmaxf(stats[C+c]/n - mu*mu, 0.f);
    float sc = g[c] * rsqrtf(var + 1e-5f);
    bnp[c] = sc;
    bnp[C+c] = be[c] - mu*sc;
  }
}

// ---------- elementwise BN+leaky+residual ----------
__global__ void k_ew_b16b16(const u16* __restrict__ agg, const u16* __restrict__ res,
                            const float* __restrict__ bnp, int C, int total, u16* __restrict__ out){
  int i = blockIdx.x*256+threadIdx.x;
  if (i < total){
    int c = i & (C-1);
    float v = b2f(agg[i])*bnp[c] + bnp[C+c];
    out[i] = f2b(leaky(v, 0.01f) + b2f(res[i]));
  }
}

__global__ void k_ew_f32f32(const float* __restrict__ agg, const float* __restrict__ res,
                            const float* __restrict__ bnp, int C, int total, float* __restrict__ out){
  int i = blockIdx.x*256+threadIdx.x;
  if (i < total){
    int c = i & (C-1);
    float v = agg[i]*bnp[c] + bnp[C+c];
    out[i] = leaky(v, 0.01f) + res[i];
  }
}

// ---------- GAT: per-head logit dot (als/ald), wave per node ----------
__global__ void k_dot64(const u16* __restrict__ h2t, const float* __restrict__ asg,
                        const float* __restrict__ adg, int head, int n,
                        float* __restrict__ als, float* __restrict__ ald){
  int nd = blockIdx.x*4 + (threadIdx.x>>6);
  if (nd>=n) return;
  int lane = threadIdx.x&63;
  float p = b2f(h2t[(size_t)nd*64+lane]);
  float ss = p*asg[lane];
  float sd = p*adg[lane];
  for (int m=1;m<64;m<<=1){ ss += __shfl_xor(ss,m,64); sd += __shfl_xor(sd,m,64); }
  if (lane==0){ als[nd*4+head]=ss; ald[nd*4+head]=sd; }
}

// ---------- GAT per-head softmax gather (online softmax + unroll-4) ----------
__global__ void k_gat_head(const u16* __restrict__ h2t, const int* __restrict__ offs,
                           const int* __restrict__ csr, const float* __restrict__ als,
                           const float* __restrict__ ald, const float* __restrict__ bg,
                           int head, int n, u16* __restrict__ O2){
  int nd = blockIdx.x*4 + (threadIdx.x>>6);
  if (nd>=n) return;
  int lane = threadIdx.x&63;
  float aldn = ald[nd*4+head];
  // online-softmax state, seeded with self-loop (weight exp(self-m)=1 at m=self)
  float m = leaky(als[nd*4+head] + aldn, 0.2f);
  float denom = 1.f;
  float acc = b2f(h2t[(size_t)nd*64+lane]);
  int e = offs[nd], end = offs[nd+1];
  for (; e+4<=end; e+=4){
    int s0=csr[e], s1=csr[e+1], s2=csr[e+2], s3=csr[e+3];
    float l0=als[s0*4+head], l1=als[s1*4+head], l2=als[s2*4+head], l3=als[s3*4+head];
    float p0=b2f(h2t[(size_t)s0*64+lane]);
    float p1=b2f(h2t[(size_t)s1*64+lane]);
    float p2=b2f(h2t[(size_t)s2*64+lane]);
    float p3=b2f(h2t[(size_t)s3*64+lane]);
    float g0=leaky(l0+aldn,0.2f), g1=leaky(l1+aldn,0.2f);
    float g2=leaky(l2+aldn,0.2f), g3=leaky(l3+aldn,0.2f);
    float mc = fmaxf(fmaxf(g0,g1), fmaxf(g2,g3));
    float mn = fmaxf(m, mc);
    float sc = __expf(m - mn);
    float w0 = __expf(g0-mn), w1 = __expf(g1-mn), w2 = __expf(g2-mn), w3 = __expf(g3-mn);
    denom = denom*sc + (w0+w1+w2+w3);
    acc   = acc*sc   + (w0*p0 + w1*p1 + w2*p2 + w3*p3);
    m = mn;
  }
  for (; e<end; ++e){
    int s = csr[e];
    float g = leaky(als[s*4+head]+aldn, 0.2f);
    float p = b2f(h2t[(size_t)s*64+lane]);
    float mn = fmaxf(m, g);
    float sc = __expf(m - mn);
    float w = __expf(g - mn);
    denom = denom*sc + w;
    acc   = acc*sc   + w*p;
    m = mn;
  }
  float v = 0.25f * acc / fmaxf(denom, 1e-20f);
  size_t oi = (size_t)nd*64+lane;
  if (head==0) O2[oi] = f2b(v + bg[lane]);
  else         O2[oi] = f2b(b2f(O2[oi]) + v);
}

// ---------- GCN aggregation, C=16 (16 threads per node), f32, unroll-4 ----------
__global__ void k_gcn_agg16(const float* __restrict__ h, const int* __restrict__ offs,
                            const int* __restrict__ csr, const float* __restrict__ dinv,
                            const float* __restrict__ bias, float* __restrict__ out, int n){
  int t = threadIdx.x;
  int nd = blockIdx.x*16 + (t>>4);
  if (nd>=n) return;
  int c = t&15;
  float dn = dinv[nd];
  float acc = dn*h[(size_t)nd*16+c];
  int e=offs[nd], end=offs[nd+1];
  for (; e+4<=end; e+=4){
    int s0=csr[e], s1=csr[e+1], s2=csr[e+2], s3=csr[e+3];
    float w0=dinv[s0], w1=dinv[s1], w2=dinv[s2], w3=dinv[s3];
    float p0=h[(size_t)s0*16+c], p1=h[(size_t)s1*16+c];
    float p2=h[(size_t)s2*16+c], p3=h[(size_t)s3*16+c];
    acc += w0*p0 + w1*p1 + w2*p2 + w3*p3;
  }
  for (; e<end; ++e){
    int s = csr[e];
    acc += dinv[s]*h[(size_t)s*16+c];
  }
  out[(size_t)nd*16+c] = dn*acc + bias[c];
}

// ---------- GCN aggregation, C=64, f32 (wave per node, unroll-4) ----------
__global__ void k_gcn_agg64f(const float* __restrict__ h, const int* __restrict__ offs,
                             const int* __restrict__ csr, const float* __restrict__ dinv,
                             const float* __restrict__ bias, float* __restrict__ out, int n){
  int nd = blockIdx.x*4 + (threadIdx.x>>6);
  if (nd>=n) return;
  int lane = threadIdx.x&63;
  float dn = dinv[nd];
  float acc = dn*h[(size_t)nd*64+lane];
  int e=offs[nd], end=offs[nd+1];
  for (; e+4<=end; e+=4){
    int s0=csr[e], s1=csr[e+1], s2=csr[e+2], s3=csr[e+3];
    float w0=dinv[s0], w1=dinv[s1], w2=dinv[s2], w3=dinv[s3];
    float p0=h[(size_t)s0*64+lane], p1=h[(size_t)s1*64+lane];
    float p2=h[(size_t)s2*64+lane], p3=h[(size_t)s3*64+lane];
    acc += w0*p0 + w1*p1 + w2*p2 + w3*p3;
  }
  for (; e<end; ++e){
    int s=csr[e];
    acc += dinv[s]*h[(size_t)s*64+lane];
  }
  out[(size_t)nd*64+lane] = dn*acc + bias[lane];
}

// ---------- small VALU GEMMs ----------
// x(N,64) bf16 -> h3(N,16)=x@W3 ; r3(N,16)=x@r3W + r3b   (weights f32)
__global__ void k_gemm64_16x2(const u16* __restrict__ x, const float* __restrict__ W1_,
                              const float* __restrict__ W2_, const float* __restrict__ b2_,
                              int n, float* __restrict__ o1, float* __restrict__ o2){
  __shared__ float w1[64*16], w2[64*16];
  int t = threadIdx.x;
  for (int i=t; i<1024; i+=256){ w1[i]=W1_[i]; w2[i]=W2_[i]; }
  __syncthreads();
  int nd = blockIdx.x*8 + (t>>5);
  if (nd>=n) return;
  int j = t & 31;
  const u16* xr = x + (size_t)nd*64;
  if (j<16){
    float s=0.f;
    #pragma unroll 8
    for (int k=0;k<64;k++) s += b2f(xr[k])*w1[k*16+j];
    o1[(size_t)nd*16+j]=s;
  } else {
    int jj=j-16;
    float s = b2_[jj];
    #pragma unroll 8
    for (int k=0;k<64;k++) s += b2f(xr[k])*w2[k*16+jj];
    o2[(size_t)nd*16+jj]=s;
  }
}

// x(N,16) f32 -> o(N,64) = x@W4 (b4 added post-aggregation); W4 f32
__global__ void k_gemm16_64(const float* __restrict__ x, const float* __restrict__ W,
                            int n, float* __restrict__ o){
  __shared__ float w[16*64];
  int t = threadIdx.x;
  for (int i=t;i<1024;i+=256) w[i]=W[i];
  __syncthreads();
  int nd = blockIdx.x*4 + (t>>6);
  if (nd>=n) return;
  int j = t&63;
  const float* xr = x + (size_t)nd*16;
  float s=0.f;
  #pragma unroll
  for (int k=0;k<16;k++) s += xr[k]*w[k*64+j];
  o[(size_t)nd*64+j]=s;
}

// out(N,64) = x(N,64)@pW + pb, f32 out
__global__ void k_final(const float* __restrict__ x, const float* __restrict__ W,
                        const float* __restrict__ b, int n, float* __restrict__ out){
  __shared__ float w[64*64];
  int t=threadIdx.x;
  for (int i=t;i<4096;i+=256) w[i]=W[i];
  __syncthreads();
  int nd = blockIdx.x*4 + (t>>6);
  if (nd>=n) return;
  int j=t&63;
  const float* xr = x + (size_t)nd*64;
  float s=b[j];
  #pragma unroll 8
  for (int k=0;k<64;k++) s += xr[k]*w[k*64+j];
  out[(size_t)nd*64+j]=s;
}

// =======================================================================
extern "C" void kernel_launch(void* const* d_in, const int* in_sizes, int n_in,
                              void* d_out, int out_size, void* d_ws, size_t ws_size,
                              hipStream_t stream) {
  const float* x   = (const float*)d_in[0];
  const int*   ei  = (const int*)d_in[1];
  const float* W1  = (const float*)d_in[2];
  const float* b1  = (const float*)d_in[3];
  const float* g1  = (const float*)d_in[4];
  const float* be1 = (const float*)d_in[5];
  const float* Wg  = (const float*)d_in[6];
  const float* a_s = (const float*)d_in[7];
  const float* a_d = (const float*)d_in[8];
  const float* bg  = (const float*)d_in[9];
  const float* g2  = (const float*)d_in[10];
  const float* be2 = (const float*)d_in[11];
  const float* W3  = (const float*)d_in[12];
  const float* b3  = (const float*)d_in[13];
  const float* g3  = (const float*)d_in[14];
  const float* be3 = (const float*)d_in[15];
  const float* W4  = (const float*)d_in[16];
  const float* b4  = (const float*)d_in[17];
  const float* r1W = (const float*)d_in[18];
  const float* r1b = (const float*)d_in[19];
  const float* r2W = (const float*)d_in[20];
  const float* r2b = (const float*)d_in[21];
  const float* r3W = (const float*)d_in[22];
  const float* r3b = (const float*)d_in[23];
  const float* pW  = (const float*)d_in[24];
  const float* pb  = (const float*)d_in[25];

  const int N = in_sizes[0] / 256;
  const int E = in_sizes[1] / 2;

  // ---- workspace carve-out: ~31 MB total ----
  char* w = (char*)d_ws;
  auto alloc = [&](size_t b)->void*{ void* p=(void*)w; w += (b+255)&~(size_t)255; return p; };
  u32*   flag   = (u32*)  alloc(4);
  float* stats1 = (float*)alloc(512*4);   // 4 tiles x 128
  float* stats2 = (float*)alloc(128*4);
  float* stats3 = (float*)alloc(32*4);
  float* bnp1   = (float*)alloc(512*4);
  float* bnp2   = (float*)alloc(128*4);
  float* bnp3   = (float*)alloc(32*4);
  int*   bsum   = (int*)  alloc(256*4);
  int*   cur    = (int*)  alloc((size_t)N*4);
  int*   offs   = (int*)  alloc((size_t)(N+1)*4);
  float* dinv   = (float*)alloc((size_t)N*4);
  int*   csr    = (int*)  alloc((size_t)E*4);
  float* als    = (float*)alloc((size_t)N*16);
  float* ald    = (float*)alloc((size_t)N*16);
  u16*   W1t    = (u16*)  alloc(65536*2);
  u16*   r1Wt   = (u16*)  alloc(65536*2);
  u16*   Wgt    = (u16*)  alloc(65536*2);
  u16*   r2Wt   = (u16*)  alloc(16384*2);
  u16*   X0     = (u16*)  alloc((size_t)N*64*2);  // x2 cols 0-63   -> x3 -> h4(lo)
  u16*   X1     = (u16*)  alloc((size_t)N*64*2);  // x2 cols 64-127 -> h3/r3 -> h4(hi)
  u16*   tA     = (u16*)  alloc((size_t)N*64*2);  // h-tile / r-tile / agg3,x4 / agg4(lo)
  u16*   tB     = (u16*)  alloc((size_t)N*64*2);  // agg-tile / O2 / agg4(hi)
  // external scratch: edge_index buffer (dead after CSR), d_out f32 (12.8MB)
  u16*   X2     = (u16*)d_in[1];                  // x2 cols 128-191
  u16*   X3     = (u16*)d_out;                    // x2 cols 192-255 (overwritten by k_final)

  const u16* XP[4] = {X0, X1, X2, X3};

  // overlay views
  float* h3   = (float*)X1;                       // N*16 f32
  float* r3   = (float*)(X1 + (size_t)N*32);      // N*16 f32
  float* agg3 = (float*)tA;                       // N*16 f32
  float* x4   = (float*)(tA + (size_t)N*32);      // N*16 f32
  float* h4   = (float*)X0;                       // N*64 f32 (spans X0+X1)
  float* agg4 = (float*)tA;                       // N*64 f32 (spans tA+tB)

  auto cdiv = [](int a, int b){ return (a+b-1)/b; };
  const int nb1024 = cdiv(N, 1024);
  const int statsGrid = 512;

  hipMemsetAsync(flag,   0, 4, stream);
  hipMemsetAsync(cur,    0, (size_t)N*4, stream);
  hipMemsetAsync(stats1, 0, 512*4, stream);
  hipMemsetAsync(stats2, 0, 128*4, stream);
  hipMemsetAsync(stats3, 0, 32*4, stream);

  k_detect<<<64,256,0,stream>>>((const u32*)ei, E, flag);

  k_transpose<<<cdiv(65536,256),256,0,stream>>>(W1,  W1t,  256,256);
  k_transpose<<<cdiv(65536,256),256,0,stream>>>(r1W, r1Wt, 256,256);
  k_transpose<<<cdiv(65536,256),256,0,stream>>>(Wg,  Wgt,  256,256);
  k_transpose<<<cdiv(16384,256),256,0,stream>>>(r2W, r2Wt, 256,64);

  // ---- CSR build (edge_index fully consumed here) ----
  k_hist  <<<cdiv(E,256),256,0,stream>>>(ei, E, N, flag, cur);
  k_scan_a<<<nb1024,256,0,stream>>>(cur, N, bsum);
  k_scan_b<<<1,64,0,stream>>>(bsum, nb1024);
  k_scan_c<<<nb1024,256,0,stream>>>(cur, bsum, N, offs);
  k_dinv2 <<<cdiv(N,256),256,0,stream>>>(offs, N, dinv);
  hipMemsetAsync(cur, 0, (size_t)N*4, stream);
  k_scatter<<<cdiv(E,256),256,0,stream>>>(ei, E, N, flag, offs, cur, csr);

  const int gemmGrid = cdiv(N,64);
  const int nodeGrid = cdiv(N,4);

  // ---- Layer 1: GCN(256->256) + BN + leaky + residual, 4 col-tiles of 64 ----
  for (int tau=0; tau<4; ++tau){
    u16* Xt = (u16*)XP[tau];
    k_gemm64<float><<<gemmGrid,256,0,stream>>>(x, x+64, x+128, x+192, 256,
                                               W1t + (size_t)tau*64*256, nullptr, tA, N);
    k_gather64<<<nodeGrid,256,0,stream>>>(tA, offs, csr, dinv, b1 + tau*64, N, tB);
    k_stats_b16<<<statsGrid,256,0,stream>>>(tB, N, 64, stats1 + tau*128);
    k_bnfin<<<1,256,0,stream>>>(stats1 + tau*128, g1 + tau*64, be1 + tau*64, 64, (float)N, bnp1 + tau*128);
    k_gemm64<float><<<gemmGrid,256,0,stream>>>(x, x+64, x+128, x+192, 256,
                                               r1Wt + (size_t)tau*64*256, r1b + tau*64, tA, N);
    k_ew_b16b16<<<cdiv(N*64,256),256,0,stream>>>(tB, tA, bnp1 + tau*128, 64, N*64, Xt);
  }

  // ---- Layer 2: GAT(256->64, 4-head mean) + BN + leaky + residual ----
  for (int head=0; head<4; ++head){
    k_gemm64<u16><<<gemmGrid,256,0,stream>>>(XP[0], XP[1], XP[2], XP[3], 64,
                                             Wgt + (size_t)head*64*256, nullptr, tA, N);
    k_dot64<<<nodeGrid,256,0,stream>>>(tA, a_s + head*64, a_d + head*64, head, N, als, ald);
    k_gat_head<<<nodeGrid,256,0,stream>>>(tA, offs, csr, als, ald, bg, head, N, tB);
  }
  k_gemm64<u16><<<gemmGrid,256,0,stream>>>(XP[0], XP[1], XP[2], XP[3], 64,
                                           r2Wt, r2b, tA, N);     // r2 -> tA (last x2 use)
  k_stats_b16<<<statsGrid,256,0,stream>>>(tB, N, 64, stats2);
  k_bnfin<<<1,256,0,stream>>>(stats2, g2, be2, 64, (float)N, bnp2);
  k_ew_b16b16<<<cdiv(N*64,256),256,0,stream>>>(tB, tA, bnp2, 64, N*64, X0);  // x3 -> X0

  // ---- Layer 3: GCN(64->16) + BN + leaky + residual ----
  k_gemm64_16x2<<<cdiv(N,8),256,0,stream>>>(X0, W3, r3W, r3b, N, h3, r3);
  k_gcn_agg16<<<cdiv(N,16),256,0,stream>>>(h3, offs, csr, dinv, b3, agg3, N);
  k_stats_f32<<<statsGrid,256,0,stream>>>(agg3, N, 16, stats3);
  k_bnfin<<<1,256,0,stream>>>(stats3, g3, be3, 16, (float)N, bnp3);
  k_ew_f32f32<<<cdiv(N*16,256),256,0,stream>>>(agg3, r3, bnp3, 16, N*16, x4);

  // ---- Layer 4: GCN(16->64), then final projection ----
  k_gemm16_64<<<nodeGrid,256,0,stream>>>(x4, W4, N, h4);
  k_gcn_agg64f<<<nodeGrid,256,0,stream>>>(h4, offs, csr, dinv, b4, agg4, N);
  k_final<<<nodeGrid,256,0,stream>>>(agg4, pW, pb, N, (float*)d_out);
}

// Round 7
// 1456.026 us; speedup vs baseline: 1.1659x; 1.1659x over previous
//
#include <hip/hip_runtime.h>

typedef unsigned short u16;
typedef unsigned int   u32;

// ---------- bf16 helpers ----------
__device__ __forceinline__ float b2f(u16 h){ return __uint_as_float(((u32)h)<<16); }
__device__ __forceinline__ u16 f2b(float f){
  u32 u = __float_as_uint(f);
  u32 r = (u + 0x7fffu + ((u>>16)&1u)) >> 16;   // RNE
  return (u16)r;
}
__device__ __forceinline__ float leaky(float x, float s){ return x >= 0.f ? x : s*x; }

typedef __bf16 bf16x8 __attribute__((ext_vector_type(8)));
typedef float  f32x4  __attribute__((ext_vector_type(4)));

__device__ __forceinline__ float ldval(const u16* p){ return b2f(*p); }
__device__ __forceinline__ float ldval(const float* p){ return *p; }

// load 8 contiguous source elems as 8 bf16 (u16)
__device__ __forceinline__ void load8(const u16* p, u16* h){ *(uint4*)h = *(const uint4*)p; }
__device__ __forceinline__ void load8(const float* p, u16* h){
  float4 a = *(const float4*)p; float4 b = *(const float4*)(p+4);
  h[0]=f2b(a.x); h[1]=f2b(a.y); h[2]=f2b(a.z); h[3]=f2b(a.w);
  h[4]=f2b(b.x); h[5]=f2b(b.y); h[6]=f2b(b.z); h[7]=f2b(b.w);
}

// ---------- int64-vs-int32 detection (odd 32b words of src row all-zero => int64) ----------
__global__ void k_detect(const u32* __restrict__ w, int E, u32* __restrict__ flag){
  u32 acc = 0;
  for (int i = blockIdx.x*256 + threadIdx.x; i < E; i += 256*gridDim.x)
    acc |= w[2*i + 1];
  __shared__ u32 s[256];
  s[threadIdx.x] = acc; __syncthreads();
  for (int o=128;o>0;o>>=1){ if (threadIdx.x<o) s[threadIdx.x] |= s[threadIdx.x+o]; __syncthreads(); }
  if (threadIdx.x==0 && s[0]) atomicOr(flag, 1u);   // nonzero -> int32
}

__device__ __forceinline__ void edge_sd(const int* __restrict__ ei, int E, int e, u32 is32,
                                        int& s, int& d){
  if (is32){ s = ei[e];   d = ei[E + e]; }
  else     { s = ei[2*e]; d = ei[2*E + 2*e]; }
}

// ---------- CSR build ----------
__global__ void k_hist(const int* __restrict__ ei, int E, int nN,
                       const u32* __restrict__ flag, int* __restrict__ cnt){
  int e = blockIdx.x*256 + threadIdx.x;
  if (e < E){
    int s,d; edge_sd(ei, E, e, *flag, s, d);
    if ((u32)s < (u32)nN && (u32)d < (u32)nN) atomicAdd(&cnt[d], 1);
  }
}

__global__ void k_scan_a(const int* __restrict__ cnt, int n, int* __restrict__ bsum){
  __shared__ int s[256];
  int base = blockIdx.x*1024, t = threadIdx.x, sum = 0;
  for (int j=0;j<4;j++){ int i = base + t*4 + j; if (i<n) sum += cnt[i]; }
  s[t] = sum; __syncthreads();
  for (int off=128; off>0; off>>=1){ if (t<off) s[t]+=s[t+off]; __syncthreads(); }
  if (t==0) bsum[blockIdx.x] = s[0];
}

__global__ void k_scan_b(int* bsum, int nb){
  if (threadIdx.x==0 && blockIdx.x==0){
    int acc = 0;
    for (int i=0;i<nb;i++){ int v = bsum[i]; bsum[i] = acc; acc += v; }
  }
}

__global__ void k_scan_c(const int* __restrict__ cnt, const int* __restrict__ bsum,
                         int n, int* __restrict__ offs){
  __shared__ int s[256];
  int base = blockIdx.x*1024, t = threadIdx.x;
  int v[4]; int sum=0;
  for (int j=0;j<4;j++){ int i=base+t*4+j; v[j] = (i<n)?cnt[i]:0; sum += v[j]; }
  s[t]=sum; __syncthreads();
  for (int off=1; off<256; off<<=1){
    int add = (t>=off)? s[t-off] : 0;
    __syncthreads();
    s[t] += add;
    __syncthreads();
  }
  int excl = (t ? s[t-1] : 0) + bsum[blockIdx.x];
  for (int j=0;j<4;j++){
    int i = base+t*4+j;
    if (i<n){ offs[i] = excl; excl += v[j]; if (i==n-1) offs[n] = excl; }
  }
}

__global__ void k_dinv2(const int* __restrict__ offs, int n, float* __restrict__ dinv){
  int i = blockIdx.x*256+threadIdx.x;
  if (i<n) dinv[i] = rsqrtf((float)(offs[i+1]-offs[i]) + 1.0f);
}

__global__ void k_scatter(const int* __restrict__ ei, int E, int nN,
                          const u32* __restrict__ flag, const int* __restrict__ offs,
                          int* __restrict__ cursor, int* __restrict__ csr){
  int e = blockIdx.x*256+threadIdx.x;
  if (e<E){
    int s,d; edge_sd(ei, E, e, *flag, s, d);
    if ((u32)s < (u32)nN && (u32)d < (u32)nN){
      int pos = offs[d] + atomicAdd(&cursor[d], 1);
      csr[pos] = s;
    }
  }
}

// ---------- transpose+convert: f32 (K x M) -> bf16 (M x K) ----------
__global__ void k_transpose(const float* __restrict__ in, u16* __restrict__ out, int K, int M){
  int i = blockIdx.x*256 + threadIdx.x;
  if (i < K*M){ int k = i / M, m = i % M; out[m*K + k] = f2b(in[i]); }
}

// ---------- MFMA GEMM: out[r][m] = sum_k A[r][k]*B[k][m] (+bias[m]); K=256, M=64 ----------
// A supplied as 4 column-pieces (64 cols each, f32 or bf16) with row stride rsA elements.
template<typename AT>
__global__ __launch_bounds__(256) void k_gemm64(
  const AT* __restrict__ A0, const AT* __restrict__ A1,
  const AT* __restrict__ A2, const AT* __restrict__ A3,
  int rsA, const u16* __restrict__ Bt, const float* __restrict__ bias,
  u16* __restrict__ out, int nRows)
{
  alignas(16) __shared__ u16 Al[64*264];
  alignas(16) __shared__ u16 Bl[32*264];
  const int t = threadIdx.x;
  const int r0 = blockIdx.x*64;
  for (int it=0; it<8; ++it){
    int c = t + it*256;
    int row = c>>5, seg = c&31;
    int gr = r0+row;
    u16 hv[8] = {0,0,0,0,0,0,0,0};
    if (gr < nRows){
      const AT* p = (seg<8)?A0 : (seg<16)?A1 : (seg<24)?A2 : A3;
      load8(p + (size_t)gr*rsA + (seg&7)*8, hv);
    }
    *(uint4*)&Al[row*264 + seg*8] = *(uint4*)hv;
  }
  const int lane=t&63, wid=t>>6, quad=lane>>4, l15=lane&15;
  const int abase=(wid*16+l15)*264 + quad*8;
  for (int cc=0; cc<2; ++cc){
    __syncthreads();
    for (int it=0; it<4; ++it){
      int c = t + it*256;
      int row=c>>5, seg=c&31;
      uint4 v = *(const uint4*)(Bt + (size_t)(cc*32+row)*256 + seg*8);
      *(uint4*)&Bl[row*264 + seg*8] = v;
    }
    __syncthreads();
    f32x4 a0={0.f,0.f,0.f,0.f}, a1={0.f,0.f,0.f,0.f};
    #pragma unroll
    for (int ks=0;ks<8;++ks){
      bf16x8 av = *(const bf16x8*)&Al[abase + ks*32];
      bf16x8 b0 = *(const bf16x8*)&Bl[(     l15)*264 + quad*8 + ks*32];
      bf16x8 b1 = *(const bf16x8*)&Bl[(16 + l15)*264 + quad*8 + ks*32];
      a0 = __builtin_amdgcn_mfma_f32_16x16x32_bf16(av,b0,a0,0,0,0);
      a1 = __builtin_amdgcn_mfma_f32_16x16x32_bf16(av,b1,a1,0,0,0);
    }
    #pragma unroll
    for (int half=0; half<2; ++half){
      f32x4 acc = half?a1:a0;
      int col = cc*32 + half*16 + l15;
      float bv = bias ? bias[col] : 0.f;
      #pragma unroll
      for (int reg=0;reg<4;++reg){
        int r = r0 + wid*16 + quad*4 + reg;   // C/D: col=lane&15, row=quad*4+reg
        if (r<nRows) out[(size_t)r*64+col] = f2b(acc[reg]+bv);
      }
    }
  }
}

// ---------- GCN gather, 64 channels, bf16 in/out (wave per node, unroll-4) ----------
__global__ void k_gather64(const u16* __restrict__ h, const int* __restrict__ offs,
                           const int* __restrict__ csr, const float* __restrict__ dinv,
                           const float* __restrict__ bias, int n, u16* __restrict__ out){
  int nd = blockIdx.x*4 + (threadIdx.x>>6);
  if (nd>=n) return;
  int lane = threadIdx.x&63;
  float dn = dinv[nd];
  float acc = dn*b2f(h[(size_t)nd*64+lane]);   // self: dn*dn*h ; factor dn applied at end
  int e = offs[nd], end = offs[nd+1];
  for (; e+4<=end; e+=4){
    int s0=csr[e], s1=csr[e+1], s2=csr[e+2], s3=csr[e+3];
    float w0=dinv[s0], w1=dinv[s1], w2=dinv[s2], w3=dinv[s3];
    float p0=b2f(h[(size_t)s0*64+lane]);
    float p1=b2f(h[(size_t)s1*64+lane]);
    float p2=b2f(h[(size_t)s2*64+lane]);
    float p3=b2f(h[(size_t)s3*64+lane]);
    acc += w0*p0 + w1*p1 + w2*p2 + w3*p3;
  }
  for (; e<end; ++e){
    int s=csr[e];
    acc += dinv[s]*b2f(h[(size_t)s*64+lane]);
  }
  out[(size_t)nd*64+lane] = f2b(dn*acc + bias[lane]);
}

// ---------- BN stats: block-local LDS reduction -> per-block partials (NO atomics) ----------
// grid B blocks x 256 threads; part[b*2C + c] = sum, part[b*2C + C + c] = sumsq
template<typename T>
__global__ void k_stats_part(const T* __restrict__ x, int n, int C,
                             float* __restrict__ part){
  int t = threadIdx.x;
  int c = t % C, sub = t / C, nsub = 256 / C;
  int rpb = (n + gridDim.x - 1) / gridDim.x;
  int base = blockIdx.x * rpb;
  int lim  = min(base + rpb, n);
  float s=0.f, s2=0.f;
  for (int row = base + sub; row < lim; row += nsub){
    float v = ldval(x + (size_t)row*C + c); s += v; s2 += v*v;
  }
  __shared__ float ls[256], lq[256];
  ls[t]=s; lq[t]=s2; __syncthreads();
  for (int off=128; off>=C; off>>=1){
    if (t < off){ ls[t]+=ls[t+off]; lq[t]+=lq[t+off]; }
    __syncthreads();
  }
  if (t < C){
    part[blockIdx.x*2*C + t]     = ls[t];
    part[blockIdx.x*2*C + C + t] = lq[t];
  }
}

// reduce partials over B blocks and produce BN scale/shift directly
__global__ void k_bnfin2(const float* __restrict__ part, int B, int C,
                         const float* __restrict__ g, const float* __restrict__ be,
                         float n, float* __restrict__ bnp){
  int c = threadIdx.x;
  if (c >= C) return;
  float s=0.f, s2=0.f;
  for (int b=0;b<B;b++){ s += part[b*2*C + c]; s2 += part[b*2*C + C + c]; }
  float mu = s/n;
  float var = fmaxf(s2/n - mu*mu, 0.f);
  float sc = g[c] * rsqrtf(var + 1e-5f);
  bnp[c] = sc;
  bnp[C+c] = be[c] - mu*sc;
}

// ---------- elementwise BN+leaky+residual ----------
__global__ void k_ew_b16b16(const u16* __restrict__ agg, const u16* __restrict__ res,
                            const float* __restrict__ bnp, int C, int total, u16* __restrict__ out){
  int i = blockIdx.x*256+threadIdx.x;
  if (i < total){
    int c = i & (C-1);
    float v = b2f(agg[i])*bnp[c] + bnp[C+c];
    out[i] = f2b(leaky(v, 0.01f) + b2f(res[i]));
  }
}

__global__ void k_ew_f32f32(const float* __restrict__ agg, const float* __restrict__ res,
                            const float* __restrict__ bnp, int C, int total, float* __restrict__ out){
  int i = blockIdx.x*256+threadIdx.x;
  if (i < total){
    int c = i & (C-1);
    float v = agg[i]*bnp[c] + bnp[C+c];
    out[i] = leaky(v, 0.01f) + res[i];
  }
}

// ---------- GAT: per-head logit dot (als/ald), wave per node ----------
__global__ void k_dot64(const u16* __restrict__ h2t, const float* __restrict__ asg,
                        const float* __restrict__ adg, int head, int n,
                        float* __restrict__ als, float* __restrict__ ald){
  int nd = blockIdx.x*4 + (threadIdx.x>>6);
  if (nd>=n) return;
  int lane = threadIdx.x&63;
  float p = b2f(h2t[(size_t)nd*64+lane]);
  float ss = p*asg[lane];
  float sd = p*adg[lane];
  for (int m=1;m<64;m<<=1){ ss += __shfl_xor(ss,m,64); sd += __shfl_xor(sd,m,64); }
  if (lane==0){ als[nd*4+head]=ss; ald[nd*4+head]=sd; }
}

// ---------- GAT per-head softmax gather (online softmax + unroll-4) ----------
__global__ void k_gat_head(const u16* __restrict__ h2t, const int* __restrict__ offs,
                           const int* __restrict__ csr, const float* __restrict__ als,
                           const float* __restrict__ ald, const float* __restrict__ bg,
                           int head, int n, u16* __restrict__ O2){
  int nd = blockIdx.x*4 + (threadIdx.x>>6);
  if (nd>=n) return;
  int lane = threadIdx.x&63;
  float aldn = ald[nd*4+head];
  // online-softmax state, seeded with self-loop (weight exp(self-m)=1 at m=self)
  float m = leaky(als[nd*4+head] + aldn, 0.2f);
  float denom = 1.f;
  float acc = b2f(h2t[(size_t)nd*64+lane]);
  int e = offs[nd], end = offs[nd+1];
  for (; e+4<=end; e+=4){
    int s0=csr[e], s1=csr[e+1], s2=csr[e+2], s3=csr[e+3];
    float l0=als[s0*4+head], l1=als[s1*4+head], l2=als[s2*4+head], l3=als[s3*4+head];
    float p0=b2f(h2t[(size_t)s0*64+lane]);
    float p1=b2f(h2t[(size_t)s1*64+lane]);
    float p2=b2f(h2t[(size_t)s2*64+lane]);
    float p3=b2f(h2t[(size_t)s3*64+lane]);
    float g0=leaky(l0+aldn,0.2f), g1=leaky(l1+aldn,0.2f);
    float g2=leaky(l2+aldn,0.2f), g3=leaky(l3+aldn,0.2f);
    float mc = fmaxf(fmaxf(g0,g1), fmaxf(g2,g3));
    float mn = fmaxf(m, mc);
    float sc = __expf(m - mn);
    float w0 = __expf(g0-mn), w1 = __expf(g1-mn), w2 = __expf(g2-mn), w3 = __expf(g3-mn);
    denom = denom*sc + (w0+w1+w2+w3);
    acc   = acc*sc   + (w0*p0 + w1*p1 + w2*p2 + w3*p3);
    m = mn;
  }
  for (; e<end; ++e){
    int s = csr[e];
    float g = leaky(als[s*4+head]+aldn, 0.2f);
    float p = b2f(h2t[(size_t)s*64+lane]);
    float mn = fmaxf(m, g);
    float sc = __expf(m - mn);
    float w = __expf(g - mn);
    denom = denom*sc + w;
    acc   = acc*sc   + w*p;
    m = mn;
  }
  float v = 0.25f * acc / fmaxf(denom, 1e-20f);
  size_t oi = (size_t)nd*64+lane;
  if (head==0) O2[oi] = f2b(v + bg[lane]);
  else         O2[oi] = f2b(b2f(O2[oi]) + v);
}

// ---------- GCN aggregation, C=16 (16 threads per node), f32, unroll-4 ----------
__global__ void k_gcn_agg16(const float* __restrict__ h, const int* __restrict__ offs,
                            const int* __restrict__ csr, const float* __restrict__ dinv,
                            const float* __restrict__ bias, float* __restrict__ out, int n){
  int t = threadIdx.x;
  int nd = blockIdx.x*16 + (t>>4);
  if (nd>=n) return;
  int c = t&15;
  float dn = dinv[nd];
  float acc = dn*h[(size_t)nd*16+c];
  int e=offs[nd], end=offs[nd+1];
  for (; e+4<=end; e+=4){
    int s0=csr[e], s1=csr[e+1], s2=csr[e+2], s3=csr[e+3];
    float w0=dinv[s0], w1=dinv[s1], w2=dinv[s2], w3=dinv[s3];
    float p0=h[(size_t)s0*16+c], p1=h[(size_t)s1*16+c];
    float p2=h[(size_t)s2*16+c], p3=h[(size_t)s3*16+c];
    acc += w0*p0 + w1*p1 + w2*p2 + w3*p3;
  }
  for (; e<end; ++e){
    int s = csr[e];
    acc += dinv[s]*h[(size_t)s*16+c];
  }
  out[(size_t)nd*16+c] = dn*acc + bias[c];
}

// ---------- GCN aggregation, C=64, f32 (wave per node, unroll-4) ----------
__global__ void k_gcn_agg64f(const float* __restrict__ h, const int* __restrict__ offs,
                             const int* __restrict__ csr, const float* __restrict__ dinv,
                             const float* __restrict__ bias, float* __restrict__ out, int n){
  int nd = blockIdx.x*4 + (threadIdx.x>>6);
  if (nd>=n) return;
  int lane = threadIdx.x&63;
  float dn = dinv[nd];
  float acc = dn*h[(size_t)nd*64+lane];
  int e=offs[nd], end=offs[nd+1];
  for (; e+4<=end; e+=4){
    int s0=csr[e], s1=csr[e+1], s2=csr[e+2], s3=csr[e+3];
    float w0=dinv[s0], w1=dinv[s1], w2=dinv[s2], w3=dinv[s3];
    float p0=h[(size_t)s0*64+lane], p1=h[(size_t)s1*64+lane];
    float p2=h[(size_t)s2*64+lane], p3=h[(size_t)s3*64+lane];
    acc += w0*p0 + w1*p1 + w2*p2 + w3*p3;
  }
  for (; e<end; ++e){
    int s=csr[e];
    acc += dinv[s]*h[(size_t)s*64+lane];
  }
  out[(size_t)nd*64+lane] = dn*acc + bias[lane];
}

// ---------- small VALU GEMMs ----------
// x(N,64) bf16 -> h3(N,16)=x@W3 ; r3(N,16)=x@r3W + r3b   (weights f32)
__global__ void k_gemm64_16x2(const u16* __restrict__ x, const float* __restrict__ W1_,
                              const float* __restrict__ W2_, const float* __restrict__ b2_,
                              int n, float* __restrict__ o1, float* __restrict__ o2){
  __shared__ float w1[64*16], w2[64*16];
  int t = threadIdx.x;
  for (int i=t; i<1024; i+=256){ w1[i]=W1_[i]; w2[i]=W2_[i]; }
  __syncthreads();
  int nd = blockIdx.x*8 + (t>>5);
  if (nd>=n) return;
  int j = t & 31;
  const u16* xr = x + (size_t)nd*64;
  if (j<16){
    float s=0.f;
    #pragma unroll 8
    for (int k=0;k<64;k++) s += b2f(xr[k])*w1[k*16+j];
    o1[(size_t)nd*16+j]=s;
  } else {
    int jj=j-16;
    float s = b2_[jj];
    #pragma unroll 8
    for (int k=0;k<64;k++) s += b2f(xr[k])*w2[k*16+jj];
    o2[(size_t)nd*16+jj]=s;
  }
}

// x(N,16) f32 -> o(N,64) = x@W4 (b4 added post-aggregation); W4 f32
__global__ void k_gemm16_64(const float* __restrict__ x, const float* __restrict__ W,
                            int n, float* __restrict__ o){
  __shared__ float w[16*64];
  int t = threadIdx.x;
  for (int i=t;i<1024;i+=256) w[i]=W[i];
  __syncthreads();
  int nd = blockIdx.x*4 + (t>>6);
  if (nd>=n) return;
  int j = t&63;
  const float* xr = x + (size_t)nd*16;
  float s=0.f;
  #pragma unroll
  for (int k=0;k<16;k++) s += xr[k]*w[k*64+j];
  o[(size_t)nd*64+j]=s;
}

// out(N,64) = x(N,64)@pW + pb, f32 out
__global__ void k_final(const float* __restrict__ x, const float* __restrict__ W,
                        const float* __restrict__ b, int n, float* __restrict__ out){
  __shared__ float w[64*64];
  int t=threadIdx.x;
  for (int i=t;i<4096;i+=256) w[i]=W[i];
  __syncthreads();
  int nd = blockIdx.x*4 + (t>>6);
  if (nd>=n) return;
  int j=t&63;
  const float* xr = x + (size_t)nd*64;
  float s=b[j];
  #pragma unroll 8
  for (int k=0;k<64;k++) s += xr[k]*w[k*64+j];
  out[(size_t)nd*64+j]=s;
}

// =======================================================================
extern "C" void kernel_launch(void* const* d_in, const int* in_sizes, int n_in,
                              void* d_out, int out_size, void* d_ws, size_t ws_size,
                              hipStream_t stream) {
  const float* x   = (const float*)d_in[0];
  const int*   ei  = (const int*)d_in[1];
  const float* W1  = (const float*)d_in[2];
  const float* b1  = (const float*)d_in[3];
  const float* g1  = (const float*)d_in[4];
  const float* be1 = (const float*)d_in[5];
  const float* Wg  = (const float*)d_in[6];
  const float* a_s = (const float*)d_in[7];
  const float* a_d = (const float*)d_in[8];
  const float* bg  = (const float*)d_in[9];
  const float* g2  = (const float*)d_in[10];
  const float* be2 = (const float*)d_in[11];
  const float* W3  = (const float*)d_in[12];
  const float* b3  = (const float*)d_in[13];
  const float* g3  = (const float*)d_in[14];
  const float* be3 = (const float*)d_in[15];
  const float* W4  = (const float*)d_in[16];
  const float* b4  = (const float*)d_in[17];
  const float* r1W = (const float*)d_in[18];
  const float* r1b = (const float*)d_in[19];
  const float* r2W = (const float*)d_in[20];
  const float* r2b = (const float*)d_in[21];
  const float* r3W = (const float*)d_in[22];
  const float* r3b = (const float*)d_in[23];
  const float* pW  = (const float*)d_in[24];
  const float* pb  = (const float*)d_in[25];

  const int N = in_sizes[0] / 256;
  const int E = in_sizes[1] / 2;

  // ---- workspace carve-out: ~31 MB total ----
  char* w = (char*)d_ws;
  auto alloc = [&](size_t b)->void*{ void* p=(void*)w; w += (b+255)&~(size_t)255; return p; };
  u32*   flag   = (u32*)  alloc(4);
  float* part   = (float*)alloc(240*128*4);       // stats partials (240 blocks x 2C, C<=64)
  float* bnp1   = (float*)alloc(512*4);           // 4 tiles x 128
  float* bnp2   = (float*)alloc(128*4);
  float* bnp3   = (float*)alloc(32*4);
  int*   bsum   = (int*)  alloc(256*4);
  int*   cur    = (int*)  alloc((size_t)N*4);
  int*   offs   = (int*)  alloc((size_t)(N+1)*4);
  float* dinv   = (float*)alloc((size_t)N*4);
  int*   csr    = (int*)  alloc((size_t)E*4);
  float* als    = (float*)alloc((size_t)N*16);
  float* ald    = (float*)alloc((size_t)N*16);
  u16*   W1t    = (u16*)  alloc(65536*2);
  u16*   r1Wt   = (u16*)  alloc(65536*2);
  u16*   Wgt    = (u16*)  alloc(65536*2);
  u16*   r2Wt   = (u16*)  alloc(16384*2);
  u16*   X0     = (u16*)  alloc((size_t)N*64*2);  // x2 cols 0-63   -> x3 -> h4(lo)
  u16*   X1     = (u16*)  alloc((size_t)N*64*2);  // x2 cols 64-127 -> h3/r3 -> h4(hi)
  u16*   tA     = (u16*)  alloc((size_t)N*64*2);  // h-tile / r-tile / agg3,x4 / agg4(lo)
  u16*   tB     = (u16*)  alloc((size_t)N*64*2);  // agg-tile / O2 / agg4(hi)
  // external scratch: edge_index buffer (dead after CSR), d_out f32 (12.8MB)
  u16*   X2     = (u16*)d_in[1];                  // x2 cols 128-191
  u16*   X3     = (u16*)d_out;                    // x2 cols 192-255 (overwritten by k_final)

  const u16* XP[4] = {X0, X1, X2, X3};

  // overlay views
  float* h3   = (float*)X1;                       // N*16 f32
  float* r3   = (float*)(X1 + (size_t)N*32);      // N*16 f32
  float* agg3 = (float*)tA;                       // N*16 f32
  float* x4   = (float*)(tA + (size_t)N*32);      // N*16 f32
  float* h4   = (float*)X0;                       // N*64 f32 (spans X0+X1)
  float* agg4 = (float*)tA;                       // N*64 f32 (spans tA+tB)

  auto cdiv = [](int a, int b){ return (a+b-1)/b; };
  const int nb1024 = cdiv(N, 1024);
  const int statsGrid = 240;

  hipMemsetAsync(flag,   0, 4, stream);
  hipMemsetAsync(cur,    0, (size_t)N*4, stream);

  k_detect<<<64,256,0,stream>>>((const u32*)ei, E, flag);

  k_transpose<<<cdiv(65536,256),256,0,stream>>>(W1,  W1t,  256,256);
  k_transpose<<<cdiv(65536,256),256,0,stream>>>(r1W, r1Wt, 256,256);
  k_transpose<<<cdiv(65536,256),256,0,stream>>>(Wg,  Wgt,  256,256);
  k_transpose<<<cdiv(16384,256),256,0,stream>>>(r2W, r2Wt, 256,64);

  // ---- CSR build (edge_index fully consumed here) ----
  k_hist  <<<cdiv(E,256),256,0,stream>>>(ei, E, N, flag, cur);
  k_scan_a<<<nb1024,256,0,stream>>>(cur, N, bsum);
  k_scan_b<<<1,64,0,stream>>>(bsum, nb1024);
  k_scan_c<<<nb1024,256,0,stream>>>(cur, bsum, N, offs);
  k_dinv2 <<<cdiv(N,256),256,0,stream>>>(offs, N, dinv);
  hipMemsetAsync(cur, 0, (size_t)N*4, stream);
  k_scatter<<<cdiv(E,256),256,0,stream>>>(ei, E, N, flag, offs, cur, csr);

  const int gemmGrid = cdiv(N,64);
  const int nodeGrid = cdiv(N,4);

  // ---- Layer 1: GCN(256->256) + BN + leaky + residual, 4 col-tiles of 64 ----
  for (int tau=0; tau<4; ++tau){
    u16* Xt = (u16*)XP[tau];
    k_gemm64<float><<<gemmGrid,256,0,stream>>>(x, x+64, x+128, x+192, 256,
                                               W1t + (size_t)tau*64*256, nullptr, tA, N);
    k_gather64<<<nodeGrid,256,0,stream>>>(tA, offs, csr, dinv, b1 + tau*64, N, tB);
    k_stats_part<u16><<<statsGrid,256,0,stream>>>(tB, N, 64, part);
    k_bnfin2<<<1,64,0,stream>>>(part, statsGrid, 64, g1 + tau*64, be1 + tau*64, (float)N, bnp1 + tau*128);
    k_gemm64<float><<<gemmGrid,256,0,stream>>>(x, x+64, x+128, x+192, 256,
                                               r1Wt + (size_t)tau*64*256, r1b + tau*64, tA, N);
    k_ew_b16b16<<<cdiv(N*64,256),256,0,stream>>>(tB, tA, bnp1 + tau*128, 64, N*64, Xt);
  }

  // ---- Layer 2: GAT(256->64, 4-head mean) + BN + leaky + residual ----
  for (int head=0; head<4; ++head){
    k_gemm64<u16><<<gemmGrid,256,0,stream>>>(XP[0], XP[1], XP[2], XP[3], 64,
                                             Wgt + (size_t)head*64*256, nullptr, tA, N);
    k_dot64<<<nodeGrid,256,0,stream>>>(tA, a_s + head*64, a_d + head*64, head, N, als, ald);
    k_gat_head<<<nodeGrid,256,0,stream>>>(tA, offs, csr, als, ald, bg, head, N, tB);
  }
  k_gemm64<u16><<<gemmGrid,256,0,stream>>>(XP[0], XP[1], XP[2], XP[3], 64,
                                           r2Wt, r2b, tA, N);     // r2 -> tA (last x2 use)
  k_stats_part<u16><<<statsGrid,256,0,stream>>>(tB, N, 64, part);
  k_bnfin2<<<1,64,0,stream>>>(part, statsGrid, 64, g2, be2, (float)N, bnp2);
  k_ew_b16b16<<<cdiv(N*64,256),256,0,stream>>>(tB, tA, bnp2, 64, N*64, X0);  // x3 -> X0

  // ---- Layer 3: GCN(64->16) + BN + leaky + residual ----
  k_gemm64_16x2<<<cdiv(N,8),256,0,stream>>>(X0, W3, r3W, r3b, N, h3, r3);
  k_gcn_agg16<<<cdiv(N,16),256,0,stream>>>(h3, offs, csr, dinv, b3, agg3, N);
  k_stats_part<float><<<statsGrid,256,0,stream>>>(agg3, N, 16, part);
  k_bnfin2<<<1,64,0,stream>>>(part, statsGrid, 16, g3, be3, (float)N, bnp3);
  k_ew_f32f32<<<cdiv(N*16,256),256,0,stream>>>(agg3, r3, bnp3, 16, N*16, x4);

  // ---- Layer 4: GCN(16->64), then final projection ----
  k_gemm16_64<<<nodeGrid,256,0,stream>>>(x4, W4, N, h4);
  k_gcn_agg64f<<<nodeGrid,256,0,stream>>>(h4, offs, csr, dinv, b4, agg4, N);
  k_final<<<nodeGrid,256,0,stream>>>(agg4, pW, pb, N, (float*)d_out);
}

// Round 8
// 1200.675 us; speedup vs baseline: 1.4138x; 1.2127x over previous
//
#include <hip/hip_runtime.h>

typedef unsigned short u16;
typedef unsigned int   u32;

// ---------- bf16 helpers ----------
__device__ __forceinline__ float b2f(u16 h){ return __uint_as_float(((u32)h)<<16); }
__device__ __forceinline__ u16 f2b(float f){
  u32 u = __float_as_uint(f);
  u32 r = (u + 0x7fffu + ((u>>16)&1u)) >> 16;   // RNE
  return (u16)r;
}
__device__ __forceinline__ float leaky(float x, float s){ return x >= 0.f ? x : s*x; }

typedef __bf16 bf16x8 __attribute__((ext_vector_type(8)));
typedef float  f32x4  __attribute__((ext_vector_type(4)));

__device__ __forceinline__ float ldval(const u16* p){ return b2f(*p); }
__device__ __forceinline__ float ldval(const float* p){ return *p; }

// load 8 contiguous source elems as 8 bf16 (u16)
__device__ __forceinline__ void load8(const u16* p, u16* h){ *(uint4*)h = *(const uint4*)p; }
__device__ __forceinline__ void load8(const float* p, u16* h){
  float4 a = *(const float4*)p; float4 b = *(const float4*)(p+4);
  h[0]=f2b(a.x); h[1]=f2b(a.y); h[2]=f2b(a.z); h[3]=f2b(a.w);
  h[4]=f2b(b.x); h[5]=f2b(b.y); h[6]=f2b(b.z); h[7]=f2b(b.w);
}

// ---------- int64-vs-int32 detection (odd 32b words of src row all-zero => int64) ----------
__global__ void k_detect(const u32* __restrict__ w, int E, u32* __restrict__ flag){
  u32 acc = 0;
  for (int i = blockIdx.x*256 + threadIdx.x; i < E; i += 256*gridDim.x)
    acc |= w[2*i + 1];
  __shared__ u32 s[256];
  s[threadIdx.x] = acc; __syncthreads();
  for (int o=128;o>0;o>>=1){ if (threadIdx.x<o) s[threadIdx.x] |= s[threadIdx.x+o]; __syncthreads(); }
  if (threadIdx.x==0 && s[0]) atomicOr(flag, 1u);   // nonzero -> int32
}

__device__ __forceinline__ void edge_sd(const int* __restrict__ ei, int E, int e, u32 is32,
                                        int& s, int& d){
  if (is32){ s = ei[e];   d = ei[E + e]; }
  else     { s = ei[2*e]; d = ei[2*E + 2*e]; }
}

// ---------- CSR build ----------
__global__ void k_hist(const int* __restrict__ ei, int E, int nN,
                       const u32* __restrict__ flag, int* __restrict__ cnt){
  int e = blockIdx.x*256 + threadIdx.x;
  if (e < E){
    int s,d; edge_sd(ei, E, e, *flag, s, d);
    if ((u32)s < (u32)nN && (u32)d < (u32)nN) atomicAdd(&cnt[d], 1);
  }
}

__global__ void k_scan_a(const int* __restrict__ cnt, int n, int* __restrict__ bsum){
  __shared__ int s[256];
  int base = blockIdx.x*1024, t = threadIdx.x, sum = 0;
  for (int j=0;j<4;j++){ int i = base + t*4 + j; if (i<n) sum += cnt[i]; }
  s[t] = sum; __syncthreads();
  for (int off=128; off>0; off>>=1){ if (t<off) s[t]+=s[t+off]; __syncthreads(); }
  if (t==0) bsum[blockIdx.x] = s[0];
}

__global__ void k_scan_b(int* bsum, int nb){
  if (threadIdx.x==0 && blockIdx.x==0){
    int acc = 0;
    for (int i=0;i<nb;i++){ int v = bsum[i]; bsum[i] = acc; acc += v; }
  }
}

__global__ void k_scan_c(const int* __restrict__ cnt, const int* __restrict__ bsum,
                         int n, int* __restrict__ offs){
  __shared__ int s[256];
  int base = blockIdx.x*1024, t = threadIdx.x;
  int v[4]; int sum=0;
  for (int j=0;j<4;j++){ int i=base+t*4+j; v[j] = (i<n)?cnt[i]:0; sum += v[j]; }
  s[t]=sum; __syncthreads();
  for (int off=1; off<256; off<<=1){
    int add = (t>=off)? s[t-off] : 0;
    __syncthreads();
    s[t] += add;
    __syncthreads();
  }
  int excl = (t ? s[t-1] : 0) + bsum[blockIdx.x];
  for (int j=0;j<4;j++){
    int i = base+t*4+j;
    if (i<n){ offs[i] = excl; excl += v[j]; if (i==n-1) offs[n] = excl; }
  }
}

__global__ void k_dinv2(const int* __restrict__ offs, int n, float* __restrict__ dinv){
  int i = blockIdx.x*256+threadIdx.x;
  if (i<n) dinv[i] = rsqrtf((float)(offs[i+1]-offs[i]) + 1.0f);
}

__global__ void k_scatter(const int* __restrict__ ei, int E, int nN,
                          const u32* __restrict__ flag, const int* __restrict__ offs,
                          int* __restrict__ cursor, int* __restrict__ csr){
  int e = blockIdx.x*256+threadIdx.x;
  if (e<E){
    int s,d; edge_sd(ei, E, e, *flag, s, d);
    if ((u32)s < (u32)nN && (u32)d < (u32)nN){
      int pos = offs[d] + atomicAdd(&cursor[d], 1);
      csr[pos] = s;
    }
  }
}

// ---------- transpose+convert: f32 (K x M) -> bf16 (M x K) ----------
__global__ void k_transpose(const float* __restrict__ in, u16* __restrict__ out, int K, int M){
  int i = blockIdx.x*256 + threadIdx.x;
  if (i < K*M){ int k = i / M, m = i % M; out[m*K + k] = f2b(in[i]); }
}

// ---------- MFMA GEMM: out[r][m] = sum_k A[r][k]*B[k][m] (+bias[m]); K=256, M=64 ----------
// A supplied as 4 column-pieces (64 cols each, f32 or bf16) with row stride rsA elements.
template<typename AT>
__global__ __launch_bounds__(256) void k_gemm64(
  const AT* __restrict__ A0, const AT* __restrict__ A1,
  const AT* __restrict__ A2, const AT* __restrict__ A3,
  int rsA, const u16* __restrict__ Bt, const float* __restrict__ bias,
  u16* __restrict__ out, int nRows)
{
  alignas(16) __shared__ u16 Al[64*264];
  alignas(16) __shared__ u16 Bl[32*264];
  const int t = threadIdx.x;
  const int r0 = blockIdx.x*64;
  for (int it=0; it<8; ++it){
    int c = t + it*256;
    int row = c>>5, seg = c&31;
    int gr = r0+row;
    u16 hv[8] = {0,0,0,0,0,0,0,0};
    if (gr < nRows){
      const AT* p = (seg<8)?A0 : (seg<16)?A1 : (seg<24)?A2 : A3;
      load8(p + (size_t)gr*rsA + (seg&7)*8, hv);
    }
    *(uint4*)&Al[row*264 + seg*8] = *(uint4*)hv;
  }
  const int lane=t&63, wid=t>>6, quad=lane>>4, l15=lane&15;
  const int abase=(wid*16+l15)*264 + quad*8;
  for (int cc=0; cc<2; ++cc){
    __syncthreads();
    for (int it=0; it<4; ++it){
      int c = t + it*256;
      int row=c>>5, seg=c&31;
      uint4 v = *(const uint4*)(Bt + (size_t)(cc*32+row)*256 + seg*8);
      *(uint4*)&Bl[row*264 + seg*8] = v;
    }
    __syncthreads();
    f32x4 a0={0.f,0.f,0.f,0.f}, a1={0.f,0.f,0.f,0.f};
    #pragma unroll
    for (int ks=0;ks<8;++ks){
      bf16x8 av = *(const bf16x8*)&Al[abase + ks*32];
      bf16x8 b0 = *(const bf16x8*)&Bl[(     l15)*264 + quad*8 + ks*32];
      bf16x8 b1 = *(const bf16x8*)&Bl[(16 + l15)*264 + quad*8 + ks*32];
      a0 = __builtin_amdgcn_mfma_f32_16x16x32_bf16(av,b0,a0,0,0,0);
      a1 = __builtin_amdgcn_mfma_f32_16x16x32_bf16(av,b1,a1,0,0,0);
    }
    #pragma unroll
    for (int half=0; half<2; ++half){
      f32x4 acc = half?a1:a0;
      int col = cc*32 + half*16 + l15;
      float bv = bias ? bias[col] : 0.f;
      #pragma unroll
      for (int reg=0;reg<4;++reg){
        int r = r0 + wid*16 + quad*4 + reg;   // C/D: col=lane&15, row=quad*4+reg
        if (r<nRows) out[(size_t)r*64+col] = f2b(acc[reg]+bv);
      }
    }
  }
}

// ---------- GCN gather, 64 channels, bf16 in/out (wave per node, unroll-4) ----------
__global__ void k_gather64(const u16* __restrict__ h, const int* __restrict__ offs,
                           const int* __restrict__ csr, const float* __restrict__ dinv,
                           const float* __restrict__ bias, int n, u16* __restrict__ out){
  int nd = blockIdx.x*4 + (threadIdx.x>>6);
  if (nd>=n) return;
  int lane = threadIdx.x&63;
  float dn = dinv[nd];
  float acc = dn*b2f(h[(size_t)nd*64+lane]);   // self: dn*dn*h ; factor dn applied at end
  int e = offs[nd], end = offs[nd+1];
  for (; e+4<=end; e+=4){
    int s0=csr[e], s1=csr[e+1], s2=csr[e+2], s3=csr[e+3];
    float w0=dinv[s0], w1=dinv[s1], w2=dinv[s2], w3=dinv[s3];
    float p0=b2f(h[(size_t)s0*64+lane]);
    float p1=b2f(h[(size_t)s1*64+lane]);
    float p2=b2f(h[(size_t)s2*64+lane]);
    float p3=b2f(h[(size_t)s3*64+lane]);
    acc += w0*p0 + w1*p1 + w2*p2 + w3*p3;
  }
  for (; e<end; ++e){
    int s=csr[e];
    acc += dinv[s]*b2f(h[(size_t)s*64+lane]);
  }
  out[(size_t)nd*64+lane] = f2b(dn*acc + bias[lane]);
}

// ---------- BN stats: block-local LDS reduction -> per-block partials (NO atomics) ----------
// grid B blocks x 256 threads; part[b*2C + c] = sum, part[b*2C + C + c] = sumsq
template<typename T>
__global__ void k_stats_part(const T* __restrict__ x, int n, int C,
                             float* __restrict__ part){
  int t = threadIdx.x;
  int c = t % C, sub = t / C, nsub = 256 / C;
  int rpb = (n + gridDim.x - 1) / gridDim.x;
  int base = blockIdx.x * rpb;
  int lim  = min(base + rpb, n);
  float s=0.f, s2=0.f;
  for (int row = base + sub; row < lim; row += nsub){
    float v = ldval(x + (size_t)row*C + c); s += v; s2 += v*v;
  }
  __shared__ float ls[256], lq[256];
  ls[t]=s; lq[t]=s2; __syncthreads();
  for (int off=128; off>=C; off>>=1){
    if (t < off){ ls[t]+=ls[t+off]; lq[t]+=lq[t+off]; }
    __syncthreads();
  }
  if (t < C){
    part[blockIdx.x*2*C + t]     = ls[t];
    part[blockIdx.x*2*C + C + t] = lq[t];
  }
}

// reduce partials over B blocks (parallel over 256 threads) and produce BN scale/shift
__global__ void k_bnfin2(const float* __restrict__ part, int B, int C,
                         const float* __restrict__ g, const float* __restrict__ be,
                         float n, float* __restrict__ bnp){
  int t = threadIdx.x;
  int c = t % C, sub = t / C, nsub = 256 / C;
  float s=0.f, s2=0.f;
  for (int b = sub; b < B; b += nsub){
    s  += part[b*2*C + c];
    s2 += part[b*2*C + C + c];
  }
  __shared__ float ls[256], lq[256];
  ls[t]=s; lq[t]=s2; __syncthreads();
  for (int off=128; off>=C; off>>=1){
    if (t < off){ ls[t]+=ls[t+off]; lq[t]+=lq[t+off]; }
    __syncthreads();
  }
  if (t < C){
    float mu = ls[t]/n;
    float var = fmaxf(lq[t]/n - mu*mu, 0.f);
    float sc = g[t] * rsqrtf(var + 1e-5f);
    bnp[t] = sc;
    bnp[C+t] = be[t] - mu*sc;
  }
}

// ---------- elementwise BN+leaky+residual ----------
__global__ void k_ew_b16b16(const u16* __restrict__ agg, const u16* __restrict__ res,
                            const float* __restrict__ bnp, int C, int total, u16* __restrict__ out){
  int i = blockIdx.x*256+threadIdx.x;
  if (i < total){
    int c = i & (C-1);
    float v = b2f(agg[i])*bnp[c] + bnp[C+c];
    out[i] = f2b(leaky(v, 0.01f) + b2f(res[i]));
  }
}

__global__ void k_ew_f32f32(const float* __restrict__ agg, const float* __restrict__ res,
                            const float* __restrict__ bnp, int C, int total, float* __restrict__ out){
  int i = blockIdx.x*256+threadIdx.x;
  if (i < total){
    int c = i & (C-1);
    float v = agg[i]*bnp[c] + bnp[C+c];
    out[i] = leaky(v, 0.01f) + res[i];
  }
}

// ---------- GAT: per-head logit dot (als/ald), wave per node ----------
__global__ void k_dot64(const u16* __restrict__ h2t, const float* __restrict__ asg,
                        const float* __restrict__ adg, int head, int n,
                        float* __restrict__ als, float* __restrict__ ald){
  int nd = blockIdx.x*4 + (threadIdx.x>>6);
  if (nd>=n) return;
  int lane = threadIdx.x&63;
  float p = b2f(h2t[(size_t)nd*64+lane]);
  float ss = p*asg[lane];
  float sd = p*adg[lane];
  for (int m=1;m<64;m<<=1){ ss += __shfl_xor(ss,m,64); sd += __shfl_xor(sd,m,64); }
  if (lane==0){ als[nd*4+head]=ss; ald[nd*4+head]=sd; }
}

// ---------- GAT per-head softmax gather (online softmax + unroll-4) ----------
__global__ void k_gat_head(const u16* __restrict__ h2t, const int* __restrict__ offs,
                           const int* __restrict__ csr, const float* __restrict__ als,
                           const float* __restrict__ ald, const float* __restrict__ bg,
                           int head, int n, u16* __restrict__ O2){
  int nd = blockIdx.x*4 + (threadIdx.x>>6);
  if (nd>=n) return;
  int lane = threadIdx.x&63;
  float aldn = ald[nd*4+head];
  // online-softmax state, seeded with self-loop (weight exp(self-m)=1 at m=self)
  float m = leaky(als[nd*4+head] + aldn, 0.2f);
  float denom = 1.f;
  float acc = b2f(h2t[(size_t)nd*64+lane]);
  int e = offs[nd], end = offs[nd+1];
  for (; e+4<=end; e+=4){
    int s0=csr[e], s1=csr[e+1], s2=csr[e+2], s3=csr[e+3];
    float l0=als[s0*4+head], l1=als[s1*4+head], l2=als[s2*4+head], l3=als[s3*4+head];
    float p0=b2f(h2t[(size_t)s0*64+lane]);
    float p1=b2f(h2t[(size_t)s1*64+lane]);
    float p2=b2f(h2t[(size_t)s2*64+lane]);
    float p3=b2f(h2t[(size_t)s3*64+lane]);
    float g0=leaky(l0+aldn,0.2f), g1=leaky(l1+aldn,0.2f);
    float g2=leaky(l2+aldn,0.2f), g3=leaky(l3+aldn,0.2f);
    float mc = fmaxf(fmaxf(g0,g1), fmaxf(g2,g3));
    float mn = fmaxf(m, mc);
    float sc = __expf(m - mn);
    float w0 = __expf(g0-mn), w1 = __expf(g1-mn), w2 = __expf(g2-mn), w3 = __expf(g3-mn);
    denom = denom*sc + (w0+w1+w2+w3);
    acc   = acc*sc   + (w0*p0 + w1*p1 + w2*p2 + w3*p3);
    m = mn;
  }
  for (; e<end; ++e){
    int s = csr[e];
    float g = leaky(als[s*4+head]+aldn, 0.2f);
    float p = b2f(h2t[(size_t)s*64+lane]);
    float mn = fmaxf(m, g);
    float sc = __expf(m - mn);
    float w = __expf(g - mn);
    denom = denom*sc + w;
    acc   = acc*sc   + w*p;
    m = mn;
  }
  float v = 0.25f * acc / fmaxf(denom, 1e-20f);
  size_t oi = (size_t)nd*64+lane;
  if (head==0) O2[oi] = f2b(v + bg[lane]);
  else         O2[oi] = f2b(b2f(O2[oi]) + v);
}

// ---------- GCN aggregation, C=16 (16 threads per node), f32, unroll-4 ----------
__global__ void k_gcn_agg16(const float* __restrict__ h, const int* __restrict__ offs,
                            const int* __restrict__ csr, const float* __restrict__ dinv,
                            const float* __restrict__ bias, float* __restrict__ out, int n){
  int t = threadIdx.x;
  int nd = blockIdx.x*16 + (t>>4);
  if (nd>=n) return;
  int c = t&15;
  float dn = dinv[nd];
  float acc = dn*h[(size_t)nd*16+c];
  int e=offs[nd], end=offs[nd+1];
  for (; e+4<=end; e+=4){
    int s0=csr[e], s1=csr[e+1], s2=csr[e+2], s3=csr[e+3];
    float w0=dinv[s0], w1=dinv[s1], w2=dinv[s2], w3=dinv[s3];
    float p0=h[(size_t)s0*16+c], p1=h[(size_t)s1*16+c];
    float p2=h[(size_t)s2*16+c], p3=h[(size_t)s3*16+c];
    acc += w0*p0 + w1*p1 + w2*p2 + w3*p3;
  }
  for (; e<end; ++e){
    int s = csr[e];
    acc += dinv[s]*h[(size_t)s*16+c];
  }
  out[(size_t)nd*16+c] = dn*acc + bias[c];
}

// ---------- GCN aggregation, C=64, f32 (wave per node, unroll-4) ----------
__global__ void k_gcn_agg64f(const float* __restrict__ h, const int* __restrict__ offs,
                             const int* __restrict__ csr, const float* __restrict__ dinv,
                             const float* __restrict__ bias, float* __restrict__ out, int n){
  int nd = blockIdx.x*4 + (threadIdx.x>>6);
  if (nd>=n) return;
  int lane = threadIdx.x&63;
  float dn = dinv[nd];
  float acc = dn*h[(size_t)nd*64+lane];
  int e=offs[nd], end=offs[nd+1];
  for (; e+4<=end; e+=4){
    int s0=csr[e], s1=csr[e+1], s2=csr[e+2], s3=csr[e+3];
    float w0=dinv[s0], w1=dinv[s1], w2=dinv[s2], w3=dinv[s3];
    float p0=h[(size_t)s0*64+lane], p1=h[(size_t)s1*64+lane];
    float p2=h[(size_t)s2*64+lane], p3=h[(size_t)s3*64+lane];
    acc += w0*p0 + w1*p1 + w2*p2 + w3*p3;
  }
  for (; e<end; ++e){
    int s=csr[e];
    acc += dinv[s]*h[(size_t)s*64+lane];
  }
  out[(size_t)nd*64+lane] = dn*acc + bias[lane];
}

// ---------- small VALU GEMMs ----------
// x(N,64) bf16 -> h3(N,16)=x@W3 ; r3(N,16)=x@r3W + r3b   (weights f32)
__global__ void k_gemm64_16x2(const u16* __restrict__ x, const float* __restrict__ W1_,
                              const float* __restrict__ W2_, const float* __restrict__ b2_,
                              int n, float* __restrict__ o1, float* __restrict__ o2){
  __shared__ float w1[64*16], w2[64*16];
  int t = threadIdx.x;
  for (int i=t; i<1024; i+=256){ w1[i]=W1_[i]; w2[i]=W2_[i]; }
  __syncthreads();
  int nd = blockIdx.x*8 + (t>>5);
  if (nd>=n) return;
  int j = t & 31;
  const u16* xr = x + (size_t)nd*64;
  if (j<16){
    float s=0.f;
    #pragma unroll 8
    for (int k=0;k<64;k++) s += b2f(xr[k])*w1[k*16+j];
    o1[(size_t)nd*16+j]=s;
  } else {
    int jj=j-16;
    float s = b2_[jj];
    #pragma unroll 8
    for (int k=0;k<64;k++) s += b2f(xr[k])*w2[k*16+jj];
    o2[(size_t)nd*16+jj]=s;
  }
}

// x(N,16) f32 -> o(N,64) = x@W4 (b4 added post-aggregation); W4 f32
__global__ void k_gemm16_64(const float* __restrict__ x, const float* __restrict__ W,
                            int n, float* __restrict__ o){
  __shared__ float w[16*64];
  int t = threadIdx.x;
  for (int i=t;i<1024;i+=256) w[i]=W[i];
  __syncthreads();
  int nd = blockIdx.x*4 + (t>>6);
  if (nd>=n) return;
  int j = t&63;
  const float* xr = x + (size_t)nd*16;
  float s=0.f;
  #pragma unroll
  for (int k=0;k<16;k++) s += xr[k]*w[k*64+j];
  o[(size_t)nd*64+j]=s;
}

// out(N,64) = x(N,64)@pW + pb, f32 out
__global__ void k_final(const float* __restrict__ x, const float* __restrict__ W,
                        const float* __restrict__ b, int n, float* __restrict__ out){
  __shared__ float w[64*64];
  int t=threadIdx.x;
  for (int i=t;i<4096;i+=256) w[i]=W[i];
  __syncthreads();
  int nd = blockIdx.x*4 + (t>>6);
  if (nd>=n) return;
  int j=t&63;
  const float* xr = x + (size_t)nd*64;
  float s=b[j];
  #pragma unroll 8
  for (int k=0;k<64;k++) s += xr[k]*w[k*64+j];
  out[(size_t)nd*64+j]=s;
}

// =======================================================================
extern "C" void kernel_launch(void* const* d_in, const int* in_sizes, int n_in,
                              void* d_out, int out_size, void* d_ws, size_t ws_size,
                              hipStream_t stream) {
  const float* x   = (const float*)d_in[0];
  const int*   ei  = (const int*)d_in[1];
  const float* W1  = (const float*)d_in[2];
  const float* b1  = (const float*)d_in[3];
  const float* g1  = (const float*)d_in[4];
  const float* be1 = (const float*)d_in[5];
  const float* Wg  = (const float*)d_in[6];
  const float* a_s = (const float*)d_in[7];
  const float* a_d = (const float*)d_in[8];
  const float* bg  = (const float*)d_in[9];
  const float* g2  = (const float*)d_in[10];
  const float* be2 = (const float*)d_in[11];
  const float* W3  = (const float*)d_in[12];
  const float* b3  = (const float*)d_in[13];
  const float* g3  = (const float*)d_in[14];
  const float* be3 = (const float*)d_in[15];
  const float* W4  = (const float*)d_in[16];
  const float* b4  = (const float*)d_in[17];
  const float* r1W = (const float*)d_in[18];
  const float* r1b = (const float*)d_in[19];
  const float* r2W = (const float*)d_in[20];
  const float* r2b = (const float*)d_in[21];
  const float* r3W = (const float*)d_in[22];
  const float* r3b = (const float*)d_in[23];
  const float* pW  = (const float*)d_in[24];
  const float* pb  = (const float*)d_in[25];

  const int N = in_sizes[0] / 256;
  const int E = in_sizes[1] / 2;

  // ---- workspace carve-out: ~31 MB total ----
  char* w = (char*)d_ws;
  auto alloc = [&](size_t b)->void*{ void* p=(void*)w; w += (b+255)&~(size_t)255; return p; };
  u32*   flag   = (u32*)  alloc(4);
  float* part   = (float*)alloc(240*128*4);       // stats partials (<=240 blocks x 2C, C<=64)
  float* bnp1   = (float*)alloc(512*4);           // 4 tiles x 128
  float* bnp2   = (float*)alloc(128*4);
  float* bnp3   = (float*)alloc(32*4);
  int*   bsum   = (int*)  alloc(256*4);
  int*   cur    = (int*)  alloc((size_t)N*4);
  int*   offs   = (int*)  alloc((size_t)(N+1)*4);
  float* dinv   = (float*)alloc((size_t)N*4);
  int*   csr    = (int*)  alloc((size_t)E*4);
  float* als    = (float*)alloc((size_t)N*16);
  float* ald    = (float*)alloc((size_t)N*16);
  u16*   W1t    = (u16*)  alloc(65536*2);
  u16*   r1Wt   = (u16*)  alloc(65536*2);
  u16*   Wgt    = (u16*)  alloc(65536*2);
  u16*   r2Wt   = (u16*)  alloc(16384*2);
  u16*   X0     = (u16*)  alloc((size_t)N*64*2);  // x2 cols 0-63   -> x3 -> h4(lo)
  u16*   X1     = (u16*)  alloc((size_t)N*64*2);  // x2 cols 64-127 -> h3/r3 -> h4(hi)
  u16*   tA     = (u16*)  alloc((size_t)N*64*2);  // h-tile / r-tile / agg3,x4 / agg4(lo)
  u16*   tB     = (u16*)  alloc((size_t)N*64*2);  // agg-tile / O2 / agg4(hi)
  // external scratch: edge_index buffer (dead after CSR), d_out f32 (12.8MB)
  u16*   X2     = (u16*)d_in[1];                  // x2 cols 128-191
  u16*   X3     = (u16*)d_out;                    // x2 cols 192-255 (overwritten by k_final)

  const u16* XP[4] = {X0, X1, X2, X3};

  // overlay views
  float* h3   = (float*)X1;                       // N*16 f32
  float* r3   = (float*)(X1 + (size_t)N*32);      // N*16 f32
  float* agg3 = (float*)tA;                       // N*16 f32
  float* x4   = (float*)(tA + (size_t)N*32);      // N*16 f32
  float* h4   = (float*)X0;                       // N*64 f32 (spans X0+X1)
  float* agg4 = (float*)tA;                       // N*64 f32 (spans tA+tB)

  auto cdiv = [](int a, int b){ return (a+b-1)/b; };
  const int nb1024 = cdiv(N, 1024);
  const int statsGrid = 128;

  hipMemsetAsync(flag,   0, 4, stream);
  hipMemsetAsync(cur,    0, (size_t)N*4, stream);

  k_detect<<<64,256,0,stream>>>((const u32*)ei, E, flag);

  k_transpose<<<cdiv(65536,256),256,0,stream>>>(W1,  W1t,  256,256);
  k_transpose<<<cdiv(65536,256),256,0,stream>>>(r1W, r1Wt, 256,256);
  k_transpose<<<cdiv(65536,256),256,0,stream>>>(Wg,  Wgt,  256,256);
  k_transpose<<<cdiv(16384,256),256,0,stream>>>(r2W, r2Wt, 256,64);

  // ---- CSR build (edge_index fully consumed here) ----
  k_hist  <<<cdiv(E,256),256,0,stream>>>(ei, E, N, flag, cur);
  k_scan_a<<<nb1024,256,0,stream>>>(cur, N, bsum);
  k_scan_b<<<1,64,0,stream>>>(bsum, nb1024);
  k_scan_c<<<nb1024,256,0,stream>>>(cur, bsum, N, offs);
  k_dinv2 <<<cdiv(N,256),256,0,stream>>>(offs, N, dinv);
  hipMemsetAsync(cur, 0, (size_t)N*4, stream);
  k_scatter<<<cdiv(E,256),256,0,stream>>>(ei, E, N, flag, offs, cur, csr);

  const int gemmGrid = cdiv(N,64);
  const int nodeGrid = cdiv(N,4);

  // ---- Layer 1: GCN(256->256) + BN + leaky + residual, 4 col-tiles of 64 ----
  for (int tau=0; tau<4; ++tau){
    u16* Xt = (u16*)XP[tau];
    k_gemm64<float><<<gemmGrid,256,0,stream>>>(x, x+64, x+128, x+192, 256,
                                               W1t + (size_t)tau*64*256, nullptr, tA, N);
    k_gather64<<<nodeGrid,256,0,stream>>>(tA, offs, csr, dinv, b1 + tau*64, N, tB);
    k_stats_part<u16><<<statsGrid,256,0,stream>>>(tB, N, 64, part);
    k_bnfin2<<<1,256,0,stream>>>(part, statsGrid, 64, g1 + tau*64, be1 + tau*64, (float)N, bnp1 + tau*128);
    k_gemm64<float><<<gemmGrid,256,0,stream>>>(x, x+64, x+128, x+192, 256,
                                               r1Wt + (size_t)tau*64*256, r1b + tau*64, tA, N);
    k_ew_b16b16<<<cdiv(N*64,256),256,0,stream>>>(tB, tA, bnp1 + tau*128, 64, N*64, Xt);
  }

  // ---- Layer 2: GAT(256->64, 4-head mean) + BN + leaky + residual ----
  for (int head=0; head<4; ++head){
    k_gemm64<u16><<<gemmGrid,256,0,stream>>>(XP[0], XP[1], XP[2], XP[3], 64,
                                             Wgt + (size_t)head*64*256, nullptr, tA, N);
    k_dot64<<<nodeGrid,256,0,stream>>>(tA, a_s + head*64, a_d + head*64, head, N, als, ald);
    k_gat_head<<<nodeGrid,256,0,stream>>>(tA, offs, csr, als, ald, bg, head, N, tB);
  }
  k_gemm64<u16><<<gemmGrid,256,0,stream>>>(XP[0], XP[1], XP[2], XP[3], 64,
                                           r2Wt, r2b, tA, N);     // r2 -> tA (last x2 use)
  k_stats_part<u16><<<statsGrid,256,0,stream>>>(tB, N, 64, part);
  k_bnfin2<<<1,256,0,stream>>>(part, statsGrid, 64, g2, be2, (float)N, bnp2);
  k_ew_b16b16<<<cdiv(N*64,256),256,0,stream>>>(tB, tA, bnp2, 64, N*64, X0);  // x3 -> X0

  // ---- Layer 3: GCN(64->16) + BN + leaky + residual ----
  k_gemm64_16x2<<<cdiv(N,8),256,0,stream>>>(X0, W3, r3W, r3b, N, h3, r3);
  k_gcn_agg16<<<cdiv(N,16),256,0,stream>>>(h3, offs, csr, dinv, b3, agg3, N);
  k_stats_part<float><<<statsGrid,256,0,stream>>>(agg3, N, 16, part);
  k_bnfin2<<<1,256,0,stream>>>(part, statsGrid, 16, g3, be3, (float)N, bnp3);
  k_ew_f32f32<<<cdiv(N*16,256),256,0,stream>>>(agg3, r3, bnp3, 16, N*16, x4);

  // ---- Layer 4: GCN(16->64), then final projection ----
  k_gemm16_64<<<nodeGrid,256,0,stream>>>(x4, W4, N, h4);
  k_gcn_agg64f<<<nodeGrid,256,0,stream>>>(h4, offs, csr, dinv, b4, agg4, N);
  k_final<<<nodeGrid,256,0,stream>>>(agg4, pW, pb, N, (float*)d_out);
}

// Round 9
// 956.949 us; speedup vs baseline: 1.7739x; 1.2547x over previous
//
#include <hip/hip_runtime.h>

typedef unsigned short u16;
typedef unsigned int   u32;

// ---------- bf16 helpers ----------
__device__ __forceinline__ float b2f(u16 h){ return __uint_as_float(((u32)h)<<16); }
__device__ __forceinline__ u16 f2b(float f){
  u32 u = __float_as_uint(f);
  u32 r = (u + 0x7fffu + ((u>>16)&1u)) >> 16;   // RNE
  return (u16)r;
}
__device__ __forceinline__ float leaky(float x, float s){ return x >= 0.f ? x : s*x; }

typedef __bf16 bf16x8 __attribute__((ext_vector_type(8)));
typedef float  f32x4  __attribute__((ext_vector_type(4)));

__device__ __forceinline__ float ldval(const u16* p){ return b2f(*p); }
__device__ __forceinline__ float ldval(const float* p){ return *p; }

__device__ __forceinline__ void load8(const u16* p, u16* h){ *(uint4*)h = *(const uint4*)p; }
__device__ __forceinline__ void load8(const float* p, u16* h){
  float4 a = *(const float4*)p; float4 b = *(const float4*)(p+4);
  h[0]=f2b(a.x); h[1]=f2b(a.y); h[2]=f2b(a.z); h[3]=f2b(a.w);
  h[4]=f2b(b.x); h[5]=f2b(b.y); h[6]=f2b(b.z); h[7]=f2b(b.w);
}

// ---------- int64-vs-int32 detection ----------
__global__ void k_detect(const u32* __restrict__ w, int E, u32* __restrict__ flag){
  u32 acc = 0;
  for (int i = blockIdx.x*256 + threadIdx.x; i < E; i += 256*gridDim.x)
    acc |= w[2*i + 1];
  __shared__ u32 s[256];
  s[threadIdx.x] = acc; __syncthreads();
  for (int o=128;o>0;o>>=1){ if (threadIdx.x<o) s[threadIdx.x] |= s[threadIdx.x+o]; __syncthreads(); }
  if (threadIdx.x==0 && s[0]) atomicOr(flag, 1u);
}

__device__ __forceinline__ void edge_sd(const int* __restrict__ ei, int E, int e, u32 is32,
                                        int& s, int& d){
  if (is32){ s = ei[e];   d = ei[E + e]; }
  else     { s = ei[2*e]; d = ei[2*E + 2*e]; }
}

// ---------- CSR build ----------
__global__ void k_hist(const int* __restrict__ ei, int E, int nN,
                       const u32* __restrict__ flag, int* __restrict__ cnt){
  int e = blockIdx.x*256 + threadIdx.x;
  if (e < E){
    int s,d; edge_sd(ei, E, e, *flag, s, d);
    if ((u32)s < (u32)nN && (u32)d < (u32)nN) atomicAdd(&cnt[d], 1);
  }
}

__global__ void k_scan_a(const int* __restrict__ cnt, int n, int* __restrict__ bsum){
  __shared__ int s[256];
  int base = blockIdx.x*1024, t = threadIdx.x, sum = 0;
  for (int j=0;j<4;j++){ int i = base + t*4 + j; if (i<n) sum += cnt[i]; }
  s[t] = sum; __syncthreads();
  for (int off=128; off>0; off>>=1){ if (t<off) s[t]+=s[t+off]; __syncthreads(); }
  if (t==0) bsum[blockIdx.x] = s[0];
}

__global__ void k_scan_b(int* bsum, int nb){
  if (threadIdx.x==0 && blockIdx.x==0){
    int acc = 0;
    for (int i=0;i<nb;i++){ int v = bsum[i]; bsum[i] = acc; acc += v; }
  }
}

__global__ void k_scan_c(const int* __restrict__ cnt, const int* __restrict__ bsum,
                         int n, int* __restrict__ offs){
  __shared__ int s[256];
  int base = blockIdx.x*1024, t = threadIdx.x;
  int v[4]; int sum=0;
  for (int j=0;j<4;j++){ int i=base+t*4+j; v[j] = (i<n)?cnt[i]:0; sum += v[j]; }
  s[t]=sum; __syncthreads();
  for (int off=1; off<256; off<<=1){
    int add = (t>=off)? s[t-off] : 0;
    __syncthreads();
    s[t] += add;
    __syncthreads();
  }
  int excl = (t ? s[t-1] : 0) + bsum[blockIdx.x];
  for (int j=0;j<4;j++){
    int i = base+t*4+j;
    if (i<n){ offs[i] = excl; excl += v[j]; if (i==n-1) offs[n] = excl; }
  }
}

__global__ void k_dinv2(const int* __restrict__ offs, int n, float* __restrict__ dinv){
  int i = blockIdx.x*256+threadIdx.x;
  if (i<n) dinv[i] = rsqrtf((float)(offs[i+1]-offs[i]) + 1.0f);
}

__global__ void k_scatter(const int* __restrict__ ei, int E, int nN,
                          const u32* __restrict__ flag, const int* __restrict__ offs,
                          int* __restrict__ cursor, int* __restrict__ csr){
  int e = blockIdx.x*256+threadIdx.x;
  if (e<E){
    int s,d; edge_sd(ei, E, e, *flag, s, d);
    if ((u32)s < (u32)nN && (u32)d < (u32)nN){
      int pos = offs[d] + atomicAdd(&cursor[d], 1);
      csr[pos] = s;
    }
  }
}

// ---------- transpose+convert: f32 (K x M) -> bf16 (M x K) ----------
__global__ void k_transpose(const float* __restrict__ in, u16* __restrict__ out, int K, int M){
  int i = blockIdx.x*256 + threadIdx.x;
  if (i < K*M){ int k = i / M, m = i % M; out[m*K + k] = f2b(in[i]); }
}

// interleave attention vectors: asi[c*4+h] = a_s[h*64+c]
__global__ void k_asdt(const float* __restrict__ a_s, const float* __restrict__ a_d,
                       float* __restrict__ asi, float* __restrict__ adi){
  int i = threadIdx.x;
  int h = i>>6, c = i&63;
  asi[c*4+h] = a_s[i];
  adi[c*4+h] = a_d[i];
}

// ---------- MFMA GEMM, M=64 ----------
template<typename AT>
__global__ __launch_bounds__(256) void k_gemm64(
  const AT* __restrict__ A0, const AT* __restrict__ A1,
  const AT* __restrict__ A2, const AT* __restrict__ A3,
  int rsA, const u16* __restrict__ Bt, const float* __restrict__ bias,
  u16* __restrict__ out, int nRows)
{
  alignas(16) __shared__ u16 Al[64*264];
  alignas(16) __shared__ u16 Bl[32*264];
  const int t = threadIdx.x;
  const int r0 = blockIdx.x*64;
  for (int it=0; it<8; ++it){
    int c = t + it*256;
    int row = c>>5, seg = c&31;
    int gr = r0+row;
    u16 hv[8] = {0,0,0,0,0,0,0,0};
    if (gr < nRows){
      const AT* p = (seg<8)?A0 : (seg<16)?A1 : (seg<24)?A2 : A3;
      load8(p + (size_t)gr*rsA + (seg&7)*8, hv);
    }
    *(uint4*)&Al[row*264 + seg*8] = *(uint4*)hv;
  }
  const int lane=t&63, wid=t>>6, quad=lane>>4, l15=lane&15;
  const int abase=(wid*16+l15)*264 + quad*8;
  for (int cc=0; cc<2; ++cc){
    __syncthreads();
    for (int it=0; it<4; ++it){
      int c = t + it*256;
      int row=c>>5, seg=c&31;
      uint4 v = *(const uint4*)(Bt + (size_t)(cc*32+row)*256 + seg*8);
      *(uint4*)&Bl[row*264 + seg*8] = v;
    }
    __syncthreads();
    f32x4 a0={0.f,0.f,0.f,0.f}, a1={0.f,0.f,0.f,0.f};
    #pragma unroll
    for (int ks=0;ks<8;++ks){
      bf16x8 av = *(const bf16x8*)&Al[abase + ks*32];
      bf16x8 b0 = *(const bf16x8*)&Bl[(     l15)*264 + quad*8 + ks*32];
      bf16x8 b1 = *(const bf16x8*)&Bl[(16 + l15)*264 + quad*8 + ks*32];
      a0 = __builtin_amdgcn_mfma_f32_16x16x32_bf16(av,b0,a0,0,0,0);
      a1 = __builtin_amdgcn_mfma_f32_16x16x32_bf16(av,b1,a1,0,0,0);
    }
    #pragma unroll
    for (int half=0; half<2; ++half){
      f32x4 acc = half?a1:a0;
      int col = cc*32 + half*16 + l15;
      float bv = bias ? bias[col] : 0.f;
      #pragma unroll
      for (int reg=0;reg<4;++reg){
        int r = r0 + wid*16 + quad*4 + reg;
        if (r<nRows) out[(size_t)r*64+col] = f2b(acc[reg]+bv);
      }
    }
  }
}

// ---------- MFMA GEMM, M=256 (A staged once; optional head-interleave epilogue) ----------
template<typename AT, bool PERM>
__global__ __launch_bounds__(256) void k_gemm256(
  const AT* __restrict__ A0, const AT* __restrict__ A1,
  const AT* __restrict__ A2, const AT* __restrict__ A3,
  int rsA, const u16* __restrict__ Bt, const float* __restrict__ bias,
  u16* __restrict__ out, int nRows)
{
  alignas(16) __shared__ u16 Al[64*264];
  alignas(16) __shared__ u16 Bl[32*264];
  const int t = threadIdx.x;
  const int r0 = blockIdx.x*64;
  for (int it=0; it<8; ++it){
    int c = t + it*256;
    int row = c>>5, seg = c&31;
    int gr = r0+row;
    u16 hv[8] = {0,0,0,0,0,0,0,0};
    if (gr < nRows){
      const AT* p = (seg<8)?A0 : (seg<16)?A1 : (seg<24)?A2 : A3;
      load8(p + (size_t)gr*rsA + (seg&7)*8, hv);
    }
    *(uint4*)&Al[row*264 + seg*8] = *(uint4*)hv;
  }
  const int lane=t&63, wid=t>>6, quad=lane>>4, l15=lane&15;
  const int abase=(wid*16+l15)*264 + quad*8;
  for (int cc=0; cc<8; ++cc){
    __syncthreads();
    for (int it=0; it<4; ++it){
      int c = t + it*256;
      int row=c>>5, seg=c&31;
      uint4 v = *(const uint4*)(Bt + (size_t)(cc*32+row)*256 + seg*8);
      *(uint4*)&Bl[row*264 + seg*8] = v;
    }
    __syncthreads();
    f32x4 a0={0.f,0.f,0.f,0.f}, a1={0.f,0.f,0.f,0.f};
    #pragma unroll
    for (int ks=0;ks<8;++ks){
      bf16x8 av = *(const bf16x8*)&Al[abase + ks*32];
      bf16x8 b0 = *(const bf16x8*)&Bl[(     l15)*264 + quad*8 + ks*32];
      bf16x8 b1 = *(const bf16x8*)&Bl[(16 + l15)*264 + quad*8 + ks*32];
      a0 = __builtin_amdgcn_mfma_f32_16x16x32_bf16(av,b0,a0,0,0,0);
      a1 = __builtin_amdgcn_mfma_f32_16x16x32_bf16(av,b1,a1,0,0,0);
    }
    #pragma unroll
    for (int half=0; half<2; ++half){
      f32x4 acc = half?a1:a0;
      int col = cc*32 + half*16 + l15;
      float bv = bias ? bias[col] : 0.f;
      int oc = PERM ? ((col&63)*4 + (col>>6)) : col;
      #pragma unroll
      for (int reg=0;reg<4;++reg){
        int r = r0 + wid*16 + quad*4 + reg;
        if (r<nRows) out[(size_t)r*256+oc] = f2b(acc[reg]+bv);
      }
    }
  }
}

// ---------- GCN gather, 64 channels (fallback path) ----------
__global__ void k_gather64(const u16* __restrict__ h, const int* __restrict__ offs,
                           const int* __restrict__ csr, const float* __restrict__ dinv,
                           const float* __restrict__ bias, int n, u16* __restrict__ out){
  int nd = blockIdx.x*4 + (threadIdx.x>>6);
  if (nd>=n) return;
  int lane = threadIdx.x&63;
  float dn = dinv[nd];
  float acc = dn*b2f(h[(size_t)nd*64+lane]);
  int e = offs[nd], end = offs[nd+1];
  for (; e+4<=end; e+=4){
    int s0=csr[e], s1=csr[e+1], s2=csr[e+2], s3=csr[e+3];
    float w0=dinv[s0], w1=dinv[s1], w2=dinv[s2], w3=dinv[s3];
    float p0=b2f(h[(size_t)s0*64+lane]);
    float p1=b2f(h[(size_t)s1*64+lane]);
    float p2=b2f(h[(size_t)s2*64+lane]);
    float p3=b2f(h[(size_t)s3*64+lane]);
    acc += w0*p0 + w1*p1 + w2*p2 + w3*p3;
  }
  for (; e<end; ++e){
    int s=csr[e];
    acc += dinv[s]*b2f(h[(size_t)s*64+lane]);
  }
  out[(size_t)nd*64+lane] = f2b(dn*acc + bias[lane]);
}

// ---------- GCN gather, 256 channels (big path, one edge walk) ----------
__global__ void k_gather256(const u16* __restrict__ h, const int* __restrict__ offs,
                            const int* __restrict__ csr, const float* __restrict__ dinv,
                            const float* __restrict__ bias, int n, u16* __restrict__ out){
  int nd = blockIdx.x*4 + (threadIdx.x>>6);
  if (nd>=n) return;
  int lane = threadIdx.x&63;
  const uint2* H = (const uint2*)h;
  float dn = dinv[nd];
  uint2 pv = H[(size_t)nd*64 + lane];
  float a0=dn*b2f(pv.x&0xffff), a1=dn*b2f(pv.x>>16);
  float a2=dn*b2f(pv.y&0xffff), a3=dn*b2f(pv.y>>16);
  int e=offs[nd], end=offs[nd+1];
  for (; e+2<=end; e+=2){
    int s0=csr[e], s1=csr[e+1];
    float w0=dinv[s0], w1=dinv[s1];
    uint2 q0=H[(size_t)s0*64+lane], q1=H[(size_t)s1*64+lane];
    a0 += w0*b2f(q0.x&0xffff) + w1*b2f(q1.x&0xffff);
    a1 += w0*b2f(q0.x>>16)    + w1*b2f(q1.x>>16);
    a2 += w0*b2f(q0.y&0xffff) + w1*b2f(q1.y&0xffff);
    a3 += w0*b2f(q0.y>>16)    + w1*b2f(q1.y>>16);
  }
  for (; e<end; ++e){
    int s=csr[e]; float w=dinv[s];
    uint2 q=H[(size_t)s*64+lane];
    a0 += w*b2f(q.x&0xffff); a1 += w*b2f(q.x>>16);
    a2 += w*b2f(q.y&0xffff); a3 += w*b2f(q.y>>16);
  }
  float4 bv = *(const float4*)(bias + lane*4);
  uint2 o;
  o.x = (u32)f2b(a0*dn + bv.x) | ((u32)f2b(a1*dn + bv.y)<<16);
  o.y = (u32)f2b(a2*dn + bv.z) | ((u32)f2b(a3*dn + bv.w)<<16);
  ((uint2*)out)[(size_t)nd*64 + lane] = o;
}

// ---------- BN stats partials (no atomics) ----------
template<typename T>
__global__ void k_stats_part(const T* __restrict__ x, int n, int C,
                             float* __restrict__ part){
  int t = threadIdx.x;
  int c = t % C, sub = t / C, nsub = 256 / C;
  int rpb = (n + gridDim.x - 1) / gridDim.x;
  int base = blockIdx.x * rpb;
  int lim  = min(base + rpb, n);
  float s=0.f, s2=0.f;
  for (int row = base + sub; row < lim; row += nsub){
    float v = ldval(x + (size_t)row*C + c); s += v; s2 += v*v;
  }
  __shared__ float ls[256], lq[256];
  ls[t]=s; lq[t]=s2; __syncthreads();
  for (int off=128; off>=C; off>>=1){
    if (t < off){ ls[t]+=ls[t+off]; lq[t]+=lq[t+off]; }
    __syncthreads();
  }
  if (t < C){
    part[blockIdx.x*2*C + t]     = ls[t];
    part[blockIdx.x*2*C + C + t] = lq[t];
  }
}

__global__ void k_bnfin2(const float* __restrict__ part, int B, int C,
                         const float* __restrict__ g, const float* __restrict__ be,
                         float n, float* __restrict__ bnp){
  int t = threadIdx.x;
  int c = t % C, sub = t / C, nsub = 256 / C;
  float s=0.f, s2=0.f;
  for (int b = sub; b < B; b += nsub){
    s  += part[b*2*C + c];
    s2 += part[b*2*C + C + c];
  }
  __shared__ float ls[256], lq[256];
  ls[t]=s; lq[t]=s2; __syncthreads();
  for (int off=128; off>=C; off>>=1){
    if (t < off){ ls[t]+=ls[t+off]; lq[t]+=lq[t+off]; }
    __syncthreads();
  }
  if (t < C){
    float mu = ls[t]/n;
    float var = fmaxf(lq[t]/n - mu*mu, 0.f);
    float sc = g[t] * rsqrtf(var + 1e-5f);
    bnp[t] = sc;
    bnp[C+t] = be[t] - mu*sc;
  }
}

// ---------- elementwise BN+leaky+residual ----------
__global__ void k_ew_b16b16(const u16* __restrict__ agg, const u16* __restrict__ res,
                            const float* __restrict__ bnp, int C, int total, u16* __restrict__ out){
  int i = blockIdx.x*256+threadIdx.x;
  if (i < total){
    int c = i & (C-1);
    float v = b2f(agg[i])*bnp[c] + bnp[C+c];
    out[i] = f2b(leaky(v, 0.01f) + b2f(res[i]));
  }
}

__global__ void k_ew_f32f32(const float* __restrict__ agg, const float* __restrict__ res,
                            const float* __restrict__ bnp, int C, int total, float* __restrict__ out){
  int i = blockIdx.x*256+threadIdx.x;
  if (i < total){
    int c = i & (C-1);
    float v = agg[i]*bnp[c] + bnp[C+c];
    out[i] = leaky(v, 0.01f) + res[i];
  }
}

// ---------- GAT fallback: per-head logit dot ----------
__global__ void k_dot64(const u16* __restrict__ h2t, const float* __restrict__ asg,
                        const float* __restrict__ adg, int head, int n,
                        float* __restrict__ als, float* __restrict__ ald){
  int nd = blockIdx.x*4 + (threadIdx.x>>6);
  if (nd>=n) return;
  int lane = threadIdx.x&63;
  float p = b2f(h2t[(size_t)nd*64+lane]);
  float ss = p*asg[lane];
  float sd = p*adg[lane];
  for (int m=1;m<64;m<<=1){ ss += __shfl_xor(ss,m,64); sd += __shfl_xor(sd,m,64); }
  if (lane==0){ als[nd*4+head]=ss; ald[nd*4+head]=sd; }
}

// ---------- GAT fallback: per-head softmax gather (online softmax) ----------
__global__ void k_gat_head(const u16* __restrict__ h2t, const int* __restrict__ offs,
                           const int* __restrict__ csr, const float* __restrict__ als,
                           const float* __restrict__ ald, const float* __restrict__ bg,
                           int head, int n, u16* __restrict__ O2){
  int nd = blockIdx.x*4 + (threadIdx.x>>6);
  if (nd>=n) return;
  int lane = threadIdx.x&63;
  float aldn = ald[nd*4+head];
  float m = leaky(als[nd*4+head] + aldn, 0.2f);
  float denom = 1.f;
  float acc = b2f(h2t[(size_t)nd*64+lane]);
  int e = offs[nd], end = offs[nd+1];
  for (; e+4<=end; e+=4){
    int s0=csr[e], s1=csr[e+1], s2=csr[e+2], s3=csr[e+3];
    float l0=als[s0*4+head], l1=als[s1*4+head], l2=als[s2*4+head], l3=als[s3*4+head];
    float p0=b2f(h2t[(size_t)s0*64+lane]);
    float p1=b2f(h2t[(size_t)s1*64+lane]);
    float p2=b2f(h2t[(size_t)s2*64+lane]);
    float p3=b2f(h2t[(size_t)s3*64+lane]);
    float g0=leaky(l0+aldn,0.2f), g1=leaky(l1+aldn,0.2f);
    float g2=leaky(l2+aldn,0.2f), g3=leaky(l3+aldn,0.2f);
    float mc = fmaxf(fmaxf(g0,g1), fmaxf(g2,g3));
    float mn = fmaxf(m, mc);
    float sc = __expf(m - mn);
    float w0 = __expf(g0-mn), w1 = __expf(g1-mn), w2 = __expf(g2-mn), w3 = __expf(g3-mn);
    denom = denom*sc + (w0+w1+w2+w3);
    acc   = acc*sc   + (w0*p0 + w1*p1 + w2*p2 + w3*p3);
    m = mn;
  }
  for (; e<end; ++e){
    int s = csr[e];
    float g = leaky(als[s*4+head]+aldn, 0.2f);
    float p = b2f(h2t[(size_t)s*64+lane]);
    float mn = fmaxf(m, g);
    float sc = __expf(m - mn);
    float w = __expf(g - mn);
    denom = denom*sc + w;
    acc   = acc*sc   + w*p;
    m = mn;
  }
  float v = 0.25f * acc / fmaxf(denom, 1e-20f);
  size_t oi = (size_t)nd*64+lane;
  if (head==0) O2[oi] = f2b(v + bg[lane]);
  else         O2[oi] = f2b(b2f(O2[oi]) + v);
}

// ---------- GAT big path: all-head logit dots (h2 interleaved) ----------
__global__ void k_dot_all(const u16* __restrict__ h2i, const float* __restrict__ asi,
                          const float* __restrict__ adi, int n,
                          float* __restrict__ als, float* __restrict__ ald){
  int nd = blockIdx.x*4 + (threadIdx.x>>6);
  if (nd>=n) return;
  int lane = threadIdx.x&63;
  uint2 pv = ((const uint2*)h2i)[(size_t)nd*64+lane];
  float p0=b2f(pv.x&0xffff), p1=b2f(pv.x>>16), p2=b2f(pv.y&0xffff), p3=b2f(pv.y>>16);
  float4 as4 = *(const float4*)(asi + lane*4);
  float4 ad4 = *(const float4*)(adi + lane*4);
  float s0=p0*as4.x, s1=p1*as4.y, s2=p2*as4.z, s3=p3*as4.w;
  float d0=p0*ad4.x, d1=p1*ad4.y, d2=p2*ad4.z, d3=p3*ad4.w;
  for (int m=1;m<64;m<<=1){
    s0+=__shfl_xor(s0,m,64); s1+=__shfl_xor(s1,m,64);
    s2+=__shfl_xor(s2,m,64); s3+=__shfl_xor(s3,m,64);
    d0+=__shfl_xor(d0,m,64); d1+=__shfl_xor(d1,m,64);
    d2+=__shfl_xor(d2,m,64); d3+=__shfl_xor(d3,m,64);
  }
  if (lane==0){
    float4 sv = {s0,s1,s2,s3}; float4 dv = {d0,d1,d2,d3};
    ((float4*)als)[nd] = sv;
    ((float4*)ald)[nd] = dv;
  }
}

// ---------- GAT big path: fused 4-head softmax gather, two-pass fixed max ----------
__global__ void k_gat_all(const u16* __restrict__ h2i, const int* __restrict__ offs,
                          const int* __restrict__ csr, const float* __restrict__ als,
                          const float* __restrict__ ald, const float* __restrict__ bg,
                          int n, u16* __restrict__ O2){
  int nd = blockIdx.x*4 + (threadIdx.x>>6);
  if (nd>=n) return;
  int lane = threadIdx.x&63;
  float4 alv = ((const float4*)als)[nd];
  float4 adv = ((const float4*)ald)[nd];
  float g0s = leaky(alv.x+adv.x,0.2f), g1s = leaky(alv.y+adv.y,0.2f);
  float g2s = leaky(alv.z+adv.z,0.2f), g3s = leaky(alv.w+adv.w,0.2f);
  float m0=g0s, m1=g1s, m2=g2s, m3=g3s;
  int beg=offs[nd], end=offs[nd+1];
  // pass 1: per-head max over incoming logits
  int e=beg;
  for (; e+4<=end; e+=4){
    int sa=csr[e], sb=csr[e+1], sc=csr[e+2], sd=csr[e+3];
    float4 la=((const float4*)als)[sa], lb=((const float4*)als)[sb];
    float4 lc=((const float4*)als)[sc], ld=((const float4*)als)[sd];
    m0 = fmaxf(fmaxf(fmaxf(m0, leaky(la.x+adv.x,0.2f)), leaky(lb.x+adv.x,0.2f)),
               fmaxf(leaky(lc.x+adv.x,0.2f), leaky(ld.x+adv.x,0.2f)));
    m1 = fmaxf(fmaxf(fmaxf(m1, leaky(la.y+adv.y,0.2f)), leaky(lb.y+adv.y,0.2f)),
               fmaxf(leaky(lc.y+adv.y,0.2f), leaky(ld.y+adv.y,0.2f)));
    m2 = fmaxf(fmaxf(fmaxf(m2, leaky(la.z+adv.z,0.2f)), leaky(lb.z+adv.z,0.2f)),
               fmaxf(leaky(lc.z+adv.z,0.2f), leaky(ld.z+adv.z,0.2f)));
    m3 = fmaxf(fmaxf(fmaxf(m3, leaky(la.w+adv.w,0.2f)), leaky(lb.w+adv.w,0.2f)),
               fmaxf(leaky(lc.w+adv.w,0.2f), leaky(ld.w+adv.w,0.2f)));
  }
  for (; e<end; ++e){
    int s=csr[e];
    float4 l=((const float4*)als)[s];
    m0 = fmaxf(m0, leaky(l.x+adv.x,0.2f));
    m1 = fmaxf(m1, leaky(l.y+adv.y,0.2f));
    m2 = fmaxf(m2, leaky(l.z+adv.z,0.2f));
    m3 = fmaxf(m3, leaky(l.w+adv.w,0.2f));
  }
  // self terms
  float d0=__expf(g0s-m0), d1=__expf(g1s-m1), d2=__expf(g2s-m2), d3=__expf(g3s-m3);
  uint2 pv = ((const uint2*)h2i)[(size_t)nd*64+lane];
  float a0=d0*b2f(pv.x&0xffff), a1=d1*b2f(pv.x>>16);
  float a2=d2*b2f(pv.y&0xffff), a3=d3*b2f(pv.y>>16);
  // pass 2: exp-weighted accumulate with fixed max
  for (e=beg; e+2<=end; e+=2){
    int sa=csr[e], sb=csr[e+1];
    float4 la=((const float4*)als)[sa], lb=((const float4*)als)[sb];
    uint2 qa=((const uint2*)h2i)[(size_t)sa*64+lane];
    uint2 qb=((const uint2*)h2i)[(size_t)sb*64+lane];
    float wa0=__expf(leaky(la.x+adv.x,0.2f)-m0), wb0=__expf(leaky(lb.x+adv.x,0.2f)-m0);
    float wa1=__expf(leaky(la.y+adv.y,0.2f)-m1), wb1=__expf(leaky(lb.y+adv.y,0.2f)-m1);
    float wa2=__expf(leaky(la.z+adv.z,0.2f)-m2), wb2=__expf(leaky(lb.z+adv.z,0.2f)-m2);
    float wa3=__expf(leaky(la.w+adv.w,0.2f)-m3), wb3=__expf(leaky(lb.w+adv.w,0.2f)-m3);
    d0 += wa0+wb0; d1 += wa1+wb1; d2 += wa2+wb2; d3 += wa3+wb3;
    a0 += wa0*b2f(qa.x&0xffff) + wb0*b2f(qb.x&0xffff);
    a1 += wa1*b2f(qa.x>>16)    + wb1*b2f(qb.x>>16);
    a2 += wa2*b2f(qa.y&0xffff) + wb2*b2f(qb.y&0xffff);
    a3 += wa3*b2f(qa.y>>16)    + wb3*b2f(qb.y>>16);
  }
  for (; e<end; ++e){
    int s=csr[e];
    float4 l=((const float4*)als)[s];
    uint2 q=((const uint2*)h2i)[(size_t)s*64+lane];
    float w0=__expf(leaky(l.x+adv.x,0.2f)-m0);
    float w1=__expf(leaky(l.y+adv.y,0.2f)-m1);
    float w2=__expf(leaky(l.z+adv.z,0.2f)-m2);
    float w3=__expf(leaky(l.w+adv.w,0.2f)-m3);
    d0+=w0; d1+=w1; d2+=w2; d3+=w3;
    a0 += w0*b2f(q.x&0xffff); a1 += w1*b2f(q.x>>16);
    a2 += w2*b2f(q.y&0xffff); a3 += w3*b2f(q.y>>16);
  }
  float v = 0.25f*(a0/d0 + a1/d1 + a2/d2 + a3/d3);
  O2[(size_t)nd*64+lane] = f2b(v + bg[lane]);
}

// ---------- GCN aggregation, C=16, f32 ----------
__global__ void k_gcn_agg16(const float* __restrict__ h, const int* __restrict__ offs,
                            const int* __restrict__ csr, const float* __restrict__ dinv,
                            const float* __restrict__ bias, float* __restrict__ out, int n){
  int t = threadIdx.x;
  int nd = blockIdx.x*16 + (t>>4);
  if (nd>=n) return;
  int c = t&15;
  float dn = dinv[nd];
  float acc = dn*h[(size_t)nd*16+c];
  int e=offs[nd], end=offs[nd+1];
  for (; e+4<=end; e+=4){
    int s0=csr[e], s1=csr[e+1], s2=csr[e+2], s3=csr[e+3];
    float w0=dinv[s0], w1=dinv[s1], w2=dinv[s2], w3=dinv[s3];
    float p0=h[(size_t)s0*16+c], p1=h[(size_t)s1*16+c];
    float p2=h[(size_t)s2*16+c], p3=h[(size_t)s3*16+c];
    acc += w0*p0 + w1*p1 + w2*p2 + w3*p3;
  }
  for (; e<end; ++e){
    int s = csr[e];
    acc += dinv[s]*h[(size_t)s*16+c];
  }
  out[(size_t)nd*16+c] = dn*acc + bias[c];
}

// ---------- GCN aggregation, C=64, f32 ----------
__global__ void k_gcn_agg64f(const float* __restrict__ h, const int* __restrict__ offs,
                             const int* __restrict__ csr, const float* __restrict__ dinv,
                             const float* __restrict__ bias, float* __restrict__ out, int n){
  int nd = blockIdx.x*4 + (threadIdx.x>>6);
  if (nd>=n) return;
  int lane = threadIdx.x&63;
  float dn = dinv[nd];
  float acc = dn*h[(size_t)nd*64+lane];
  int e=offs[nd], end=offs[nd+1];
  for (; e+4<=end; e+=4){
    int s0=csr[e], s1=csr[e+1], s2=csr[e+2], s3=csr[e+3];
    float w0=dinv[s0], w1=dinv[s1], w2=dinv[s2], w3=dinv[s3];
    float p0=h[(size_t)s0*64+lane], p1=h[(size_t)s1*64+lane];
    float p2=h[(size_t)s2*64+lane], p3=h[(size_t)s3*64+lane];
    acc += w0*p0 + w1*p1 + w2*p2 + w3*p3;
  }
  for (; e<end; ++e){
    int s=csr[e];
    acc += dinv[s]*h[(size_t)s*64+lane];
  }
  out[(size_t)nd*64+lane] = dn*acc + bias[lane];
}

// ---------- small VALU GEMMs ----------
__global__ void k_gemm64_16x2(const u16* __restrict__ x, const float* __restrict__ W1_,
                              const float* __restrict__ W2_, const float* __restrict__ b2_,
                              int n, float* __restrict__ o1, float* __restrict__ o2){
  __shared__ float w1[64*16], w2[64*16];
  int t = threadIdx.x;
  for (int i=t; i<1024; i+=256){ w1[i]=W1_[i]; w2[i]=W2_[i]; }
  __syncthreads();
  int nd = blockIdx.x*8 + (t>>5);
  if (nd>=n) return;
  int j = t & 31;
  const u16* xr = x + (size_t)nd*64;
  if (j<16){
    float s=0.f;
    #pragma unroll 8
    for (int k=0;k<64;k++) s += b2f(xr[k])*w1[k*16+j];
    o1[(size_t)nd*16+j]=s;
  } else {
    int jj=j-16;
    float s = b2_[jj];
    #pragma unroll 8
    for (int k=0;k<64;k++) s += b2f(xr[k])*w2[k*16+jj];
    o2[(size_t)nd*16+jj]=s;
  }
}

__global__ void k_gemm16_64(const float* __restrict__ x, const float* __restrict__ W,
                            int n, float* __restrict__ o){
  __shared__ float w[16*64];
  int t = threadIdx.x;
  for (int i=t;i<1024;i+=256) w[i]=W[i];
  __syncthreads();
  int nd = blockIdx.x*4 + (t>>6);
  if (nd>=n) return;
  int j = t&63;
  const float* xr = x + (size_t)nd*16;
  float s=0.f;
  #pragma unroll
  for (int k=0;k<16;k++) s += xr[k]*w[k*64+j];
  o[(size_t)nd*64+j]=s;
}

// out(N,64) = x(N,64)@pW + pb, f32 out (safe in-place per-wave)
__global__ void k_final(const float* __restrict__ x, const float* __restrict__ W,
                        const float* __restrict__ b, int n, float* __restrict__ out){
  __shared__ float w[64*64];
  int t=threadIdx.x;
  for (int i=t;i<4096;i+=256) w[i]=W[i];
  __syncthreads();
  int nd = blockIdx.x*4 + (t>>6);
  if (nd>=n) return;
  int j=t&63;
  const float* xr = x + (size_t)nd*64;
  float s=b[j];
  #pragma unroll 8
  for (int k=0;k<64;k++) s += xr[k]*w[k*64+j];
  out[(size_t)nd*64+j]=s;
}

// =======================================================================
extern "C" void kernel_launch(void* const* d_in, const int* in_sizes, int n_in,
                              void* d_out, int out_size, void* d_ws, size_t ws_size,
                              hipStream_t stream) {
  const float* x   = (const float*)d_in[0];
  const int*   ei  = (const int*)d_in[1];
  const float* W1  = (const float*)d_in[2];
  const float* b1  = (const float*)d_in[3];
  const float* g1  = (const float*)d_in[4];
  const float* be1 = (const float*)d_in[5];
  const float* Wg  = (const float*)d_in[6];
  const float* a_s = (const float*)d_in[7];
  const float* a_d = (const float*)d_in[8];
  const float* bg  = (const float*)d_in[9];
  const float* g2  = (const float*)d_in[10];
  const float* be2 = (const float*)d_in[11];
  const float* W3  = (const float*)d_in[12];
  const float* b3  = (const float*)d_in[13];
  const float* g3  = (const float*)d_in[14];
  const float* be3 = (const float*)d_in[15];
  const float* W4  = (const float*)d_in[16];
  const float* b4  = (const float*)d_in[17];
  const float* r1W = (const float*)d_in[18];
  const float* r1b = (const float*)d_in[19];
  const float* r2W = (const float*)d_in[20];
  const float* r2b = (const float*)d_in[21];
  const float* r3W = (const float*)d_in[22];
  const float* r3b = (const float*)d_in[23];
  const float* pW  = (const float*)d_in[24];
  const float* pb  = (const float*)d_in[25];

  const int N = in_sizes[0] / 256;
  const int E = in_sizes[1] / 2;

  // ---- common misc carve-out ----
  char* w = (char*)d_ws;
  auto alloc = [&](size_t b)->void*{ void* p=(void*)w; w += (b+255)&~(size_t)255; return p; };
  u32*   flag   = (u32*)  alloc(4);
  float* part   = (float*)alloc(128*512*4);       // stats partials (128 blocks x 2C, C<=256)
  float* bnp1   = (float*)alloc(512*4);
  float* bnp2   = (float*)alloc(128*4);
  float* bnp3   = (float*)alloc(32*4);
  int*   bsum   = (int*)  alloc(256*4);
  int*   cur    = (int*)  alloc((size_t)N*4);
  int*   offs   = (int*)  alloc((size_t)(N+1)*4);
  float* dinv   = (float*)alloc((size_t)N*4);
  int*   csr    = (int*)  alloc((size_t)E*4);
  float* als    = (float*)alloc((size_t)N*16);
  float* ald    = (float*)alloc((size_t)N*16);
  float* asi    = (float*)alloc(256*4);
  float* adi    = (float*)alloc(256*4);
  u16*   W1t    = (u16*)  alloc(65536*2);
  u16*   r1Wt   = (u16*)  alloc(65536*2);
  u16*   Wgt    = (u16*)  alloc(65536*2);
  u16*   r2Wt   = (u16*)  alloc(16384*2);

  auto cdiv = [](int a, int b){ return (a+b-1)/b; };
  const int nb1024 = cdiv(N, 1024);
  const int statsGrid = 128;
  const int gemmGrid = cdiv(N,64);
  const int nodeGrid = cdiv(N,4);

  hipMemsetAsync(flag,   0, 4, stream);
  hipMemsetAsync(cur,    0, (size_t)N*4, stream);

  k_detect<<<64,256,0,stream>>>((const u32*)ei, E, flag);

  k_transpose<<<cdiv(65536,256),256,0,stream>>>(W1,  W1t,  256,256);
  k_transpose<<<cdiv(65536,256),256,0,stream>>>(r1W, r1Wt, 256,256);
  k_transpose<<<cdiv(65536,256),256,0,stream>>>(Wg,  Wgt,  256,256);
  k_transpose<<<cdiv(16384,256),256,0,stream>>>(r2W, r2Wt, 256,64);
  k_asdt<<<1,256,0,stream>>>(a_s, a_d, asi, adi);

  // ---- CSR build (edge_index fully consumed here) ----
  k_hist  <<<cdiv(E,256),256,0,stream>>>(ei, E, N, flag, cur);
  k_scan_a<<<nb1024,256,0,stream>>>(cur, N, bsum);
  k_scan_b<<<1,64,0,stream>>>(bsum, nb1024);
  k_scan_c<<<nb1024,256,0,stream>>>(cur, bsum, N, offs);
  k_dinv2 <<<cdiv(N,256),256,0,stream>>>(offs, N, dinv);
  hipMemsetAsync(cur, 0, (size_t)N*4, stream);
  k_scatter<<<cdiv(E,256),256,0,stream>>>(ei, E, N, flag, offs, cur, csr);

  size_t miscUsed = (size_t)(w - (char*)d_ws);
  size_t bigNeed  = miscUsed + 2*((size_t)N*512) + 1024;  // two N*256 bf16 regions

  if (ws_size >= bigNeed){
    // ================= BIG PATH (fused full-width) =================
    u16* RA = (u16*)alloc((size_t)N*512);   // H1 -> R1 -> H2i ; then h3/r3/agg3/x4 (f32)
    u16* RB = (u16*)alloc((size_t)N*512);   // AGG1 -> X2 ; then h4 (f32)
    u16* tAe = (u16*)d_in[1];               // edge buffer: O2 -> x3 (N*64 bf16)
    u16* r2d = (u16*)d_out;                 // r2 (N*64 bf16), later agg4 f32

    float* h3   = (float*)RA;
    float* r3   = (float*)(RA + (size_t)N*32);
    float* agg3 = (float*)(RA + (size_t)N*64);
    float* x4   = (float*)(RA + (size_t)N*96);
    float* h4   = (float*)RB;
    float* agg4 = (float*)d_out;

    // Layer 1: GCN(256->256)
    k_gemm256<float,false><<<gemmGrid,256,0,stream>>>(x, x+64, x+128, x+192, 256,
                                                      W1t, nullptr, RA, N);          // H1
    k_gather256<<<nodeGrid,256,0,stream>>>(RA, offs, csr, dinv, b1, N, RB);          // AGG1
    k_stats_part<u16><<<statsGrid,256,0,stream>>>(RB, N, 256, part);
    k_bnfin2<<<1,256,0,stream>>>(part, statsGrid, 256, g1, be1, (float)N, bnp1);
    k_gemm256<float,false><<<gemmGrid,256,0,stream>>>(x, x+64, x+128, x+192, 256,
                                                      r1Wt, r1b, RA, N);             // R1
    k_ew_b16b16<<<cdiv(N*256,256),256,0,stream>>>(RB, RA, bnp1, 256, N*256, RB);     // X2

    // Layer 2: GAT fused
    k_gemm256<u16,true><<<gemmGrid,256,0,stream>>>(RB, RB+64, RB+128, RB+192, 256,
                                                   Wgt, nullptr, RA, N);             // H2 interleaved
    k_gemm64<u16><<<gemmGrid,256,0,stream>>>(RB, RB+64, RB+128, RB+192, 256,
                                             r2Wt, r2b, r2d, N);                     // r2
    k_dot_all<<<nodeGrid,256,0,stream>>>(RA, asi, adi, N, als, ald);
    k_gat_all<<<nodeGrid,256,0,stream>>>(RA, offs, csr, als, ald, bg, N, tAe);       // O2
    k_stats_part<u16><<<statsGrid,256,0,stream>>>(tAe, N, 64, part);
    k_bnfin2<<<1,256,0,stream>>>(part, statsGrid, 64, g2, be2, (float)N, bnp2);
    k_ew_b16b16<<<cdiv(N*64,256),256,0,stream>>>(tAe, r2d, bnp2, 64, N*64, tAe);     // x3

    // Layer 3
    k_gemm64_16x2<<<cdiv(N,8),256,0,stream>>>(tAe, W3, r3W, r3b, N, h3, r3);
    k_gcn_agg16<<<cdiv(N,16),256,0,stream>>>(h3, offs, csr, dinv, b3, agg3, N);
    k_stats_part<float><<<statsGrid,256,0,stream>>>(agg3, N, 16, part);
    k_bnfin2<<<1,256,0,stream>>>(part, statsGrid, 16, g3, be3, (float)N, bnp3);
    k_ew_f32f32<<<cdiv(N*16,256),256,0,stream>>>(agg3, r3, bnp3, 16, N*16, x4);

    // Layer 4
    k_gemm16_64<<<nodeGrid,256,0,stream>>>(x4, W4, N, h4);
    k_gcn_agg64f<<<nodeGrid,256,0,stream>>>(h4, offs, csr, dinv, b4, agg4, N);
    k_final<<<nodeGrid,256,0,stream>>>(agg4, pW, pb, N, (float*)d_out);
  } else {
    // ================= FALLBACK (round-8 structure) =================
    u16* X0 = (u16*)alloc((size_t)N*64*2);
    u16* X1 = (u16*)alloc((size_t)N*64*2);
    u16* tA = (u16*)alloc((size_t)N*64*2);
    u16* tB = (u16*)alloc((size_t)N*64*2);
    u16* X2 = (u16*)d_in[1];
    u16* X3 = (u16*)d_out;
    const u16* XP[4] = {X0, X1, X2, X3};

    float* h3   = (float*)X1;
    float* r3   = (float*)(X1 + (size_t)N*32);
    float* agg3 = (float*)tA;
    float* x4   = (float*)(tA + (size_t)N*32);
    float* h4   = (float*)X0;
    float* agg4 = (float*)tA;

    for (int tau=0; tau<4; ++tau){
      u16* Xt = (u16*)XP[tau];
      k_gemm64<float><<<gemmGrid,256,0,stream>>>(x, x+64, x+128, x+192, 256,
                                                 W1t + (size_t)tau*64*256, nullptr, tA, N);
      k_gather64<<<nodeGrid,256,0,stream>>>(tA, offs, csr, dinv, b1 + tau*64, N, tB);
      k_stats_part<u16><<<statsGrid,256,0,stream>>>(tB, N, 64, part);
      k_bnfin2<<<1,256,0,stream>>>(part, statsGrid, 64, g1 + tau*64, be1 + tau*64, (float)N, bnp1 + tau*128);
      k_gemm64<float><<<gemmGrid,256,0,stream>>>(x, x+64, x+128, x+192, 256,
                                                 r1Wt + (size_t)tau*64*256, r1b + tau*64, tA, N);
      k_ew_b16b16<<<cdiv(N*64,256),256,0,stream>>>(tB, tA, bnp1 + tau*128, 64, N*64, Xt);
    }

    for (int head=0; head<4; ++head){
      k_gemm64<u16><<<gemmGrid,256,0,stream>>>(XP[0], XP[1], XP[2], XP[3], 64,
                                               Wgt + (size_t)head*64*256, nullptr, tA, N);
      k_dot64<<<nodeGrid,256,0,stream>>>(tA, a_s + head*64, a_d + head*64, head, N, als, ald);
      k_gat_head<<<nodeGrid,256,0,stream>>>(tA, offs, csr, als, ald, bg, head, N, tB);
    }
    k_gemm64<u16><<<gemmGrid,256,0,stream>>>(XP[0], XP[1], XP[2], XP[3], 64,
                                             r2Wt, r2b, tA, N);
    k_stats_part<u16><<<statsGrid,256,0,stream>>>(tB, N, 64, part);
    k_bnfin2<<<1,256,0,stream>>>(part, statsGrid, 64, g2, be2, (float)N, bnp2);
    k_ew_b16b16<<<cdiv(N*64,256),256,0,stream>>>(tB, tA, bnp2, 64, N*64, X0);

    k_gemm64_16x2<<<cdiv(N,8),256,0,stream>>>(X0, W3, r3W, r3b, N, h3, r3);
    k_gcn_agg16<<<cdiv(N,16),256,0,stream>>>(h3, offs, csr, dinv, b3, agg3, N);
    k_stats_part<float><<<statsGrid,256,0,stream>>>(agg3, N, 16, part);
    k_bnfin2<<<1,256,0,stream>>>(part, statsGrid, 16, g3, be3, (float)N, bnp3);
    k_ew_f32f32<<<cdiv(N*16,256),256,0,stream>>>(agg3, r3, bnp3, 16, N*16, x4);

    k_gemm16_64<<<nodeGrid,256,0,stream>>>(x4, W4, N, h4);
    k_gcn_agg64f<<<nodeGrid,256,0,stream>>>(h4, offs, csr, dinv, b4, agg4, N);
    k_final<<<nodeGrid,256,0,stream>>>(agg4, pW, pb, N, (float*)d_out);
  }
}